// Round 1
// baseline (2461.374 us; speedup 1.0000x reference)
//
#include <hip/hip_runtime.h>

// Problem constants
#define BB 16
#define CCH 512
#define CQD 32
#define HH 32
#define WW 32
#define NN 1024

// ---------------------------------------------------------------------------
// conv_qk: C_out=32 3x3 SAME conv. grid(8 rowtiles, 2 which, 16 b), block 256.
// which=0: q = conv(x,wq,bq); which=1: k = conv(y,wk,bk)
// ---------------------------------------------------------------------------
__global__ __launch_bounds__(256) void conv_qk_kernel(
    const float* __restrict__ x, const float* __restrict__ y,
    const float* __restrict__ wq, const float* __restrict__ bq,
    const float* __restrict__ wk, const float* __restrict__ bk,
    float* __restrict__ qout, float* __restrict__ kout)
{
    const int rt    = blockIdx.x;        // output rows rt*4 .. rt*4+3
    const int which = blockIdx.y;
    const int b     = blockIdx.z;
    const float* in   = which ? y  : x;
    const float* wgt  = which ? wk : wq;
    const float* bias = which ? bk : bq;
    float* out        = which ? kout : qout;

    __shared__ __align__(16) float Wl[32][289];    // [co][ci*9+tap], +1 pad (bank)
    __shared__ __align__(16) float Xl[32][6][36];  // [ci][row][col], zero-padded halo

    const int t    = threadIdx.x;
    const int co   = t & 31;
    const int grp  = t >> 5;            // 8 groups of 16 px
    const int rr   = grp >> 1;          // local out row 0..3
    const int col0 = (grp & 1) * 16;    // col offset 0 or 16

    float acc[16];
    {
        float bv = bias[co];
        #pragma unroll
        for (int i = 0; i < 16; ++i) acc[i] = bv;
    }

    #pragma unroll 1
    for (int ci0 = 0; ci0 < CCH; ci0 += 32) {
        __syncthreads();
        // stage W: 32 co x 288 floats (coalesced: 288 contiguous per co)
        for (int idx = t; idx < 32 * 288; idx += 256) {
            int c = idx / 288, r = idx - c * 288;
            Wl[c][r] = wgt[c * 4608 + ci0 * 9 + r];
        }
        // stage X with zero halo: 32 ci x 6 rows x 36 cols
        for (int idx = t; idx < 32 * 216; idx += 256) {
            int ci = idx / 216, rem = idx - ci * 216;
            int r = rem / 36, c = rem - r * 36;
            int gr = rt * 4 - 1 + r;
            int gc = c - 1;
            float v = 0.f;
            if (gr >= 0 && gr < HH && gc >= 0 && gc < WW)
                v = in[((size_t)(b * CCH + ci0 + ci) * HH + gr) * WW + gc];
            Xl[ci][r][c] = v;
        }
        __syncthreads();

        #pragma unroll 1
        for (int ci = 0; ci < 32; ++ci) {
            #pragma unroll
            for (int dh = 0; dh < 3; ++dh) {
                float xr[20];
                #pragma unroll
                for (int v4 = 0; v4 < 5; ++v4) {
                    float4 xv = *(const float4*)&Xl[ci][rr + dh][col0 + v4 * 4];
                    xr[v4*4+0] = xv.x; xr[v4*4+1] = xv.y;
                    xr[v4*4+2] = xv.z; xr[v4*4+3] = xv.w;
                }
                float w0 = Wl[co][ci * 9 + dh * 3 + 0];
                float w1 = Wl[co][ci * 9 + dh * 3 + 1];
                float w2 = Wl[co][ci * 9 + dh * 3 + 2];
                #pragma unroll
                for (int cc = 0; cc < 16; ++cc)
                    acc[cc] += w0 * xr[cc] + w1 * xr[cc + 1] + w2 * xr[cc + 2];
            }
        }
    }

    // write: 16 contiguous floats per thread
    float* o = &out[((size_t)(b * CQD + co) * NN) + (rt * 4 + rr) * WW + col0];
    #pragma unroll
    for (int v4 = 0; v4 < 4; ++v4) {
        float4 ov = make_float4(acc[v4*4+0], acc[v4*4+1], acc[v4*4+2], acc[v4*4+3]);
        *(float4*)&o[v4 * 4] = ov;
    }
}

// ---------------------------------------------------------------------------
// conv_v: C_out=512 3x3 SAME conv. grid(8 rowtiles, 8 cotiles, 16 b), block 256.
// Each thread: 1 co x 32 px (one full output row).
// ---------------------------------------------------------------------------
__global__ __launch_bounds__(256) void conv_v_kernel(
    const float* __restrict__ y, const float* __restrict__ wv,
    const float* __restrict__ bvb, float* __restrict__ vout)
{
    const int rt  = blockIdx.x;        // rows rt*4..rt*4+3
    const int co0 = blockIdx.y * 64;
    const int b   = blockIdx.z;

    __shared__ __align__(16) float Wl[64][145];    // [co][ci*9+tap]
    __shared__ __align__(16) float Xl[16][6][36];

    const int t  = threadIdx.x;
    const int co = t & 63;
    const int rr = t >> 6;             // 0..3

    float acc[32];
    {
        float bv = bvb[co0 + co];
        #pragma unroll
        for (int i = 0; i < 32; ++i) acc[i] = bv;
    }

    #pragma unroll 1
    for (int ci0 = 0; ci0 < CCH; ci0 += 16) {
        __syncthreads();
        for (int idx = t; idx < 64 * 144; idx += 256) {
            int c = idx / 144, r = idx - c * 144;
            Wl[c][r] = wv[(size_t)(co0 + c) * 4608 + ci0 * 9 + r];
        }
        for (int idx = t; idx < 16 * 216; idx += 256) {
            int ci = idx / 216, rem = idx - ci * 216;
            int r = rem / 36, c = rem - r * 36;
            int gr = rt * 4 - 1 + r;
            int gc = c - 1;
            float v = 0.f;
            if (gr >= 0 && gr < HH && gc >= 0 && gc < WW)
                v = y[((size_t)(b * CCH + ci0 + ci) * HH + gr) * WW + gc];
            Xl[ci][r][c] = v;
        }
        __syncthreads();

        #pragma unroll 1
        for (int ci = 0; ci < 16; ++ci) {
            #pragma unroll
            for (int dh = 0; dh < 3; ++dh) {
                float xr[36];
                #pragma unroll
                for (int v4 = 0; v4 < 9; ++v4) {
                    float4 xv = *(const float4*)&Xl[ci][rr + dh][v4 * 4];
                    xr[v4*4+0] = xv.x; xr[v4*4+1] = xv.y;
                    xr[v4*4+2] = xv.z; xr[v4*4+3] = xv.w;
                }
                float w0 = Wl[co][ci * 9 + dh * 3 + 0];
                float w1 = Wl[co][ci * 9 + dh * 3 + 1];
                float w2 = Wl[co][ci * 9 + dh * 3 + 2];
                #pragma unroll
                for (int cc = 0; cc < 32; ++cc)
                    acc[cc] += w0 * xr[cc] + w1 * xr[cc + 1] + w2 * xr[cc + 2];
            }
        }
    }

    float* o = &vout[((size_t)(b) * CCH + co0 + co) * NN + (rt * 4 + rr) * WW];
    #pragma unroll
    for (int v4 = 0; v4 < 8; ++v4) {
        float4 ov = make_float4(acc[v4*4+0], acc[v4*4+1], acc[v4*4+2], acc[v4*4+3]);
        *(float4*)&o[v4 * 4] = ov;
    }
}

// ---------------------------------------------------------------------------
// stats: per (b,i) softmax row stats m=max_j S, l=sum_j exp(S-m).
// grid(16 itiles, 16 b), block 256. i-tile=64, 4 j-splits per query.
// ---------------------------------------------------------------------------
__global__ __launch_bounds__(256) void stats_kernel(
    const float* __restrict__ q, const float* __restrict__ k,
    float* __restrict__ sm, float* __restrict__ sl)
{
    const int i0 = blockIdx.x * 64;
    const int b  = blockIdx.y;

    __shared__ __align__(16) float qT[64][36];
    __shared__ __align__(16) float kT[128][36];
    __shared__ float redm[4][64];
    __shared__ float redl[4][64];

    const int t = threadIdx.x;
    for (int idx = t; idx < 64 * 32; idx += 256) {
        int ii = idx & 63, d = idx >> 6;
        qT[ii][d] = q[((size_t)b * CQD + d) * NN + i0 + ii];
    }
    __syncthreads();

    const int il = t & 63, js = t >> 6;
    float qr[32];
    #pragma unroll
    for (int v4 = 0; v4 < 8; ++v4) {
        float4 qv = *(const float4*)&qT[il][v4 * 4];
        qr[v4*4+0] = qv.x; qr[v4*4+1] = qv.y; qr[v4*4+2] = qv.z; qr[v4*4+3] = qv.w;
    }

    float m = -1e30f, l = 0.f;
    #pragma unroll 1
    for (int jc = 0; jc < 8; ++jc) {
        __syncthreads();
        for (int idx = t; idx < 128 * 32; idx += 256) {
            int jj = idx & 127, d = idx >> 7;
            kT[jj][d] = k[((size_t)b * CQD + d) * NN + jc * 128 + jj];
        }
        __syncthreads();
        #pragma unroll 1
        for (int u = 0; u < 32; ++u) {
            int jj = js * 32 + u;
            float s = 0.f;
            #pragma unroll
            for (int v4 = 0; v4 < 8; ++v4) {
                float4 kv = *(const float4*)&kT[jj][v4 * 4];
                s += qr[v4*4+0]*kv.x + qr[v4*4+1]*kv.y + qr[v4*4+2]*kv.z + qr[v4*4+3]*kv.w;
            }
            if (s > m) { l = l * __expf(m - s) + 1.f; m = s; }
            else       { l += __expf(s - m); }
        }
    }
    redm[js][il] = m;
    redl[js][il] = l;
    __syncthreads();
    if (t < 64) {
        float M = redm[0][t];
        #pragma unroll
        for (int u = 1; u < 4; ++u) M = fmaxf(M, redm[u][t]);
        float L = 0.f;
        #pragma unroll
        for (int u = 0; u < 4; ++u) L += redl[u][t] * __expf(redm[u][t] - M);
        sm[(size_t)b * NN + i0 + t] = M;
        sl[(size_t)b * NN + i0 + t] = L;
    }
}

// ---------------------------------------------------------------------------
// attn_pv: recompute S per tile, P = exp(S-m)/l, out += V.P^T.
// grid(4 cgroups of 128, 32 itiles of 32, 16 b), block 256.
// ---------------------------------------------------------------------------
__global__ __launch_bounds__(256) void attn_pv_kernel(
    const float* __restrict__ q, const float* __restrict__ k,
    const float* __restrict__ v, const float* __restrict__ sm,
    const float* __restrict__ sl, float* __restrict__ out)
{
    const int c0 = blockIdx.x * 128;
    const int i0 = blockIdx.y * 32;
    const int b  = blockIdx.z;

    __shared__ __align__(16) float qT[32][36];
    __shared__ __align__(16) float kT[64][36];
    __shared__ __align__(16) float vT[64][132];   // [j][c], padded
    __shared__ __align__(16) float pT[64][36];    // [j][i]

    const int t = threadIdx.x;
    for (int idx = t; idx < 32 * 32; idx += 256) {
        int ii = idx & 31, d = idx >> 5;
        qT[ii][d] = q[((size_t)b * CQD + d) * NN + i0 + ii];
    }
    __syncthreads();

    const int is = t & 31;   // query row for S phase; c-group for PV phase
    const int jg = t >> 5;   // j-group for S phase; i-group for PV phase

    float qr[32];
    #pragma unroll
    for (int v4 = 0; v4 < 8; ++v4) {
        float4 qv = *(const float4*)&qT[is][v4 * 4];
        qr[v4*4+0] = qv.x; qr[v4*4+1] = qv.y; qr[v4*4+2] = qv.z; qr[v4*4+3] = qv.w;
    }
    const float mr = sm[(size_t)b * NN + i0 + is];
    const float rl = 1.f / sl[(size_t)b * NN + i0 + is];

    float acc[4][4];
    #pragma unroll
    for (int a = 0; a < 4; ++a)
        #pragma unroll
        for (int bb = 0; bb < 4; ++bb) acc[a][bb] = 0.f;

    #pragma unroll 1
    for (int jc = 0; jc < 16; ++jc) {
        const int j0 = jc * 64;
        __syncthreads();
        for (int idx = t; idx < 64 * 32; idx += 256) {
            int jj = idx & 63, d = idx >> 6;
            kT[jj][d] = k[((size_t)b * CQD + d) * NN + j0 + jj];
        }
        for (int idx = t; idx < 64 * 128; idx += 256) {
            int jj = idx & 63, c = idx >> 6;
            vT[jj][c] = v[((size_t)b * CCH + c0 + c) * NN + j0 + jj];
        }
        __syncthreads();
        // S phase: each thread 8 j's for query row `is`
        #pragma unroll
        for (int u = 0; u < 8; ++u) {
            int jj = jg * 8 + u;
            float s = 0.f;
            #pragma unroll
            for (int v4 = 0; v4 < 8; ++v4) {
                float4 kv = *(const float4*)&kT[jj][v4 * 4];
                s += qr[v4*4+0]*kv.x + qr[v4*4+1]*kv.y + qr[v4*4+2]*kv.z + qr[v4*4+3]*kv.w;
            }
            pT[jj][is] = __expf(s - mr) * rl;
        }
        __syncthreads();
        // PV phase: acc[c4][i4] += v[c,j]*p[i,j]
        #pragma unroll 4
        for (int jj = 0; jj < 64; ++jj) {
            float4 vv = *(const float4*)&vT[jj][is * 4];
            float4 pp = *(const float4*)&pT[jj][jg * 4];
            acc[0][0] += vv.x * pp.x; acc[0][1] += vv.x * pp.y;
            acc[0][2] += vv.x * pp.z; acc[0][3] += vv.x * pp.w;
            acc[1][0] += vv.y * pp.x; acc[1][1] += vv.y * pp.y;
            acc[1][2] += vv.y * pp.z; acc[1][3] += vv.y * pp.w;
            acc[2][0] += vv.z * pp.x; acc[2][1] += vv.z * pp.y;
            acc[2][2] += vv.z * pp.z; acc[2][3] += vv.z * pp.w;
            acc[3][0] += vv.w * pp.x; acc[3][1] += vv.w * pp.y;
            acc[3][2] += vv.w * pp.z; acc[3][3] += vv.w * pp.w;
        }
    }

    #pragma unroll
    for (int a = 0; a < 4; ++a) {
        float4 ov = make_float4(acc[a][0], acc[a][1], acc[a][2], acc[a][3]);
        *(float4*)&out[((size_t)b * CCH + c0 + is * 4 + a) * NN + i0 + jg * 4] = ov;
    }
}

// ---------------------------------------------------------------------------
extern "C" void kernel_launch(void* const* d_in, const int* in_sizes, int n_in,
                              void* d_out, int out_size, void* d_ws, size_t ws_size,
                              hipStream_t stream) {
    const float* x  = (const float*)d_in[0];
    const float* y  = (const float*)d_in[1];
    const float* wq = (const float*)d_in[2];
    const float* bq = (const float*)d_in[3];
    const float* wk = (const float*)d_in[4];
    const float* bk = (const float*)d_in[5];
    const float* wv = (const float*)d_in[6];
    const float* bv = (const float*)d_in[7];
    float* out = (float*)d_out;

    // workspace layout (floats): q | k | v | sm | sl  (~38 MB total)
    float* ws  = (float*)d_ws;
    float* qb  = ws;
    float* kb  = qb + (size_t)BB * CQD * NN;
    float* vb  = kb + (size_t)BB * CQD * NN;
    float* smb = vb + (size_t)BB * CCH * NN;
    float* slb = smb + (size_t)BB * NN;

    conv_qk_kernel<<<dim3(8, 2, BB), 256, 0, stream>>>(x, y, wq, bq, wk, bk, qb, kb);
    conv_v_kernel<<<dim3(8, 8, BB), 256, 0, stream>>>(y, wv, bv, vb);
    stats_kernel<<<dim3(16, BB), 256, 0, stream>>>(qb, kb, smb, slb);
    attn_pv_kernel<<<dim3(4, 32, BB), 256, 0, stream>>>(qb, kb, vb, smb, slb, out);
}

// Round 2
// 1067.032 us; speedup vs baseline: 2.3067x; 2.3067x over previous
//
#include <hip/hip_runtime.h>

// Problem constants
#define BB 16
#define CCH 512
#define CQD 32
#define HH 32
#define WW 32
#define NN 1024

typedef __attribute__((ext_vector_type(8))) short short8v;
typedef __attribute__((ext_vector_type(8))) unsigned short ushort8v;
typedef __attribute__((ext_vector_type(4))) unsigned short ushort4v;
typedef __attribute__((ext_vector_type(4))) float f32x4;

static __device__ __forceinline__ unsigned short f2bf(float f) {
    unsigned int u = __float_as_uint(f);
    u = (u + 0x7FFFu + ((u >> 16) & 1u)) >> 16;   // RNE
    return (unsigned short)u;
}
static __device__ __forceinline__ float bf2f(unsigned short u) {
    return __uint_as_float(((unsigned int)u) << 16);
}

// ---------------------------------------------------------------------------
// prep_y: y[b][ci][h][w] fp32 -> ybf[b][h][w][ci] bf16 (ci contiguous)
// grid(32 h, 16 b), block 256
// ---------------------------------------------------------------------------
__global__ __launch_bounds__(256) void prep_y_kernel(
    const float* __restrict__ y, unsigned short* __restrict__ ybf)
{
    const int h = blockIdx.x, b = blockIdx.y;
    __shared__ float X[64][33];
    const int t = threadIdx.x;
    for (int ci0 = 0; ci0 < CCH; ci0 += 64) {
        __syncthreads();
        #pragma unroll
        for (int i = 0; i < 8; ++i) {
            int ci = i * 8 + (t >> 5), w = t & 31;
            X[ci][w] = y[((size_t)(b * CCH + ci0 + ci) * HH + h) * WW + w];
        }
        __syncthreads();
        int w = t >> 3, g = t & 7;
        ushort8v o;
        #pragma unroll
        for (int u = 0; u < 8; ++u) o[u] = f2bf(X[g * 8 + u][w]);
        *(ushort8v*)&ybf[(((size_t)b * HH + h) * WW + w) * CCH + ci0 + g * 8] = o;
    }
}

// ---------------------------------------------------------------------------
// prep_w: wv[co][ci][3][3] fp32 -> wvb[co][tap*512+ci] bf16
// grid(512 co), block 256
// ---------------------------------------------------------------------------
__global__ __launch_bounds__(256) void prep_w_kernel(
    const float* __restrict__ wv, unsigned short* __restrict__ wvb)
{
    const int co = blockIdx.x;
    for (int idx = threadIdx.x; idx < 4608; idx += 256) {
        int tap = idx / 512, ci = idx - tap * 512;
        wvb[(size_t)co * 4608 + idx] = f2bf(wv[(size_t)co * 4608 + ci * 9 + tap]);
    }
}

// ---------------------------------------------------------------------------
// conv_v_mfma: implicit-GEMM 3x3 conv via bf16 MFMA.
// Block: 64 co x 256 px (8 image rows). 4 waves, each 64co x 64px (4x4 frags).
// grid(4 pxtiles, 8 cotiles, 16 b), block 256.
// Output v in bf16 [b][co][px].
// ---------------------------------------------------------------------------
__global__ __launch_bounds__(256, 2) void conv_v_mfma_kernel(
    const unsigned short* __restrict__ ybf,   // [b][h][w][ci]
    const unsigned short* __restrict__ wvb,   // [co][tap*512+ci]
    const float* __restrict__ bvb,
    unsigned short* __restrict__ vout)        // bf16 [b][co][px]
{
    const int pt  = blockIdx.x;          // image rows pt*8 .. pt*8+7
    const int co0 = blockIdx.y * 64;
    const int b   = blockIdx.z;

    // Wl: [64 co][9 tap * 32 ci + 8 pad]  (592B/row -> 2-way banks on A reads)
    // Yl: [10 rows][34 cols][32 ci + 8 pad] (80B/col -> 2-way banks on B reads)
    __shared__ unsigned short Wl[64 * 296];
    __shared__ unsigned short Yl[10 * 34 * 40];

    const int t    = threadIdx.x;
    const int lane = t & 63;
    const int wv4  = t >> 6;             // wave id 0..3
    const int l15  = lane & 15;
    const int kg   = lane >> 4;          // k-group 0..3

    f32x4 acc[4][4];
    #pragma unroll
    for (int m = 0; m < 4; ++m)
        #pragma unroll
        for (int n = 0; n < 4; ++n) {
            f32x4 z = {0.f, 0.f, 0.f, 0.f};
            acc[m][n] = z;
        }

    const int r0 = pt * 8;
    // B-fragment base LDS offsets (elements) per px-frag n
    int bbase[4];
    #pragma unroll
    for (int n = 0; n < 4; ++n) {
        int pxl = wv4 * 64 + n * 16 + l15;     // 0..255 local px
        int rl = pxl >> 5, cl = pxl & 31;
        bbase[n] = (rl * 34 + cl) * 40 + kg * 8;
    }
    // A-fragment base offsets per co-frag m
    int abase[4];
    #pragma unroll
    for (int m = 0; m < 4; ++m)
        abase[m] = (m * 16 + l15) * 296 + kg * 8;

    #pragma unroll 1
    for (int ci0 = 0; ci0 < CCH; ci0 += 32) {
        __syncthreads();
        // stage W: 64co x 9tap x 32ci = 2304 x 16B ops
        #pragma unroll
        for (int i = 0; i < 9; ++i) {
            int idx = t + i * 256;
            int c = idx / 36, rem = idx - c * 36;
            int tap = rem >> 2, part = rem & 3;
            ushort8v v = *(const ushort8v*)&wvb[(size_t)(co0 + c) * 4608 + tap * 512 + ci0 + part * 8];
            *(ushort8v*)&Wl[c * 296 + tap * 32 + part * 8] = v;
        }
        // stage Y: 10 rows x 34 cols x 32ci = 1360 x 16B ops, zero halo
        for (int idx = t; idx < 1360; idx += 256) {
            int hw = idx >> 2, part = idx & 3;
            int r = hw / 34, c = hw - r * 34;
            int gh = r0 - 1 + r, gw = c - 1;
            ushort8v v;
            if (gh >= 0 && gh < HH && gw >= 0 && gw < WW) {
                v = *(const ushort8v*)&ybf[(((size_t)b * HH + gh) * WW + gw) * CCH + ci0 + part * 8];
            } else {
                #pragma unroll
                for (int u = 0; u < 8; ++u) v[u] = 0;
            }
            *(ushort8v*)&Yl[(r * 34 + c) * 40 + part * 8] = v;
        }
        __syncthreads();

        #pragma unroll
        for (int tap = 0; tap < 9; ++tap) {
            const int dh = tap / 3, dw = tap % 3;
            short8v a[4], bf[4];
            #pragma unroll
            for (int m = 0; m < 4; ++m)
                a[m] = *(const short8v*)&Wl[abase[m] + tap * 32];
            #pragma unroll
            for (int n = 0; n < 4; ++n)
                bf[n] = *(const short8v*)&Yl[bbase[n] + (dh * 34 + dw) * 40];
            #pragma unroll
            for (int m = 0; m < 4; ++m)
                #pragma unroll
                for (int n = 0; n < 4; ++n)
                    acc[m][n] = __builtin_amdgcn_mfma_f32_16x16x32_bf16(a[m], bf[n], acc[m][n], 0, 0, 0);
        }
    }

    // epilogue: D[row=co=(kg*4+reg)][col=px=l15] per frag; add bias, store bf16
    #pragma unroll
    for (int m = 0; m < 4; ++m) {
        #pragma unroll
        for (int reg = 0; reg < 4; ++reg) {
            int co = co0 + m * 16 + kg * 4 + reg;
            float bias = bvb[co];
            #pragma unroll
            for (int n = 0; n < 4; ++n) {
                int px = pt * 256 + wv4 * 64 + n * 16 + l15;
                vout[((size_t)b * CCH + co) * NN + px] = f2bf(acc[m][n][reg] + bias);
            }
        }
    }
}

// ---------------------------------------------------------------------------
// conv_qk: C_out=32 3x3 SAME conv (unchanged from round 1).
// ---------------------------------------------------------------------------
__global__ __launch_bounds__(256) void conv_qk_kernel(
    const float* __restrict__ x, const float* __restrict__ y,
    const float* __restrict__ wq, const float* __restrict__ bq,
    const float* __restrict__ wk, const float* __restrict__ bk,
    float* __restrict__ qout, float* __restrict__ kout)
{
    const int rt    = blockIdx.x;
    const int which = blockIdx.y;
    const int b     = blockIdx.z;
    const float* in   = which ? y  : x;
    const float* wgt  = which ? wk : wq;
    const float* bias = which ? bk : bq;
    float* out        = which ? kout : qout;

    __shared__ __align__(16) float Wl[32][289];
    __shared__ __align__(16) float Xl[32][6][36];

    const int t    = threadIdx.x;
    const int co   = t & 31;
    const int grp  = t >> 5;
    const int rr   = grp >> 1;
    const int col0 = (grp & 1) * 16;

    float acc[16];
    {
        float bv = bias[co];
        #pragma unroll
        for (int i = 0; i < 16; ++i) acc[i] = bv;
    }

    #pragma unroll 1
    for (int ci0 = 0; ci0 < CCH; ci0 += 32) {
        __syncthreads();
        for (int idx = t; idx < 32 * 288; idx += 256) {
            int c = idx / 288, r = idx - c * 288;
            Wl[c][r] = wgt[c * 4608 + ci0 * 9 + r];
        }
        for (int idx = t; idx < 32 * 216; idx += 256) {
            int ci = idx / 216, rem = idx - ci * 216;
            int r = rem / 36, c = rem - r * 36;
            int gr = rt * 4 - 1 + r;
            int gc = c - 1;
            float v = 0.f;
            if (gr >= 0 && gr < HH && gc >= 0 && gc < WW)
                v = in[((size_t)(b * CCH + ci0 + ci) * HH + gr) * WW + gc];
            Xl[ci][r][c] = v;
        }
        __syncthreads();

        #pragma unroll 1
        for (int ci = 0; ci < 32; ++ci) {
            #pragma unroll
            for (int dh = 0; dh < 3; ++dh) {
                float xr[20];
                #pragma unroll
                for (int v4 = 0; v4 < 5; ++v4) {
                    float4 xv = *(const float4*)&Xl[ci][rr + dh][col0 + v4 * 4];
                    xr[v4*4+0] = xv.x; xr[v4*4+1] = xv.y;
                    xr[v4*4+2] = xv.z; xr[v4*4+3] = xv.w;
                }
                float w0 = Wl[co][ci * 9 + dh * 3 + 0];
                float w1 = Wl[co][ci * 9 + dh * 3 + 1];
                float w2 = Wl[co][ci * 9 + dh * 3 + 2];
                #pragma unroll
                for (int cc = 0; cc < 16; ++cc)
                    acc[cc] += w0 * xr[cc] + w1 * xr[cc + 1] + w2 * xr[cc + 2];
            }
        }
    }

    float* o = &out[((size_t)(b * CQD + co) * NN) + (rt * 4 + rr) * WW + col0];
    #pragma unroll
    for (int v4 = 0; v4 < 4; ++v4) {
        float4 ov = make_float4(acc[v4*4+0], acc[v4*4+1], acc[v4*4+2], acc[v4*4+3]);
        *(float4*)&o[v4 * 4] = ov;
    }
}

// ---------------------------------------------------------------------------
// stats: per (b,i) softmax row stats (unchanged from round 1).
// ---------------------------------------------------------------------------
__global__ __launch_bounds__(256) void stats_kernel(
    const float* __restrict__ q, const float* __restrict__ k,
    float* __restrict__ sm, float* __restrict__ sl)
{
    const int i0 = blockIdx.x * 64;
    const int b  = blockIdx.y;

    __shared__ __align__(16) float qT[64][36];
    __shared__ __align__(16) float kT[128][36];
    __shared__ float redm[4][64];
    __shared__ float redl[4][64];

    const int t = threadIdx.x;
    for (int idx = t; idx < 64 * 32; idx += 256) {
        int ii = idx & 63, d = idx >> 6;
        qT[ii][d] = q[((size_t)b * CQD + d) * NN + i0 + ii];
    }
    __syncthreads();

    const int il = t & 63, js = t >> 6;
    float qr[32];
    #pragma unroll
    for (int v4 = 0; v4 < 8; ++v4) {
        float4 qv = *(const float4*)&qT[il][v4 * 4];
        qr[v4*4+0] = qv.x; qr[v4*4+1] = qv.y; qr[v4*4+2] = qv.z; qr[v4*4+3] = qv.w;
    }

    float m = -1e30f, l = 0.f;
    #pragma unroll 1
    for (int jc = 0; jc < 8; ++jc) {
        __syncthreads();
        for (int idx = t; idx < 128 * 32; idx += 256) {
            int jj = idx & 127, d = idx >> 7;
            kT[jj][d] = k[((size_t)b * CQD + d) * NN + jc * 128 + jj];
        }
        __syncthreads();
        #pragma unroll 1
        for (int u = 0; u < 32; ++u) {
            int jj = js * 32 + u;
            float s = 0.f;
            #pragma unroll
            for (int v4 = 0; v4 < 8; ++v4) {
                float4 kv = *(const float4*)&kT[jj][v4 * 4];
                s += qr[v4*4+0]*kv.x + qr[v4*4+1]*kv.y + qr[v4*4+2]*kv.z + qr[v4*4+3]*kv.w;
            }
            if (s > m) { l = l * __expf(m - s) + 1.f; m = s; }
            else       { l += __expf(s - m); }
        }
    }
    redm[js][il] = m;
    redl[js][il] = l;
    __syncthreads();
    if (t < 64) {
        float M = redm[0][t];
        #pragma unroll
        for (int u = 1; u < 4; ++u) M = fmaxf(M, redm[u][t]);
        float L = 0.f;
        #pragma unroll
        for (int u = 0; u < 4; ++u) L += redl[u][t] * __expf(redm[u][t] - M);
        sm[(size_t)b * NN + i0 + t] = M;
        sl[(size_t)b * NN + i0 + t] = L;
    }
}

// ---------------------------------------------------------------------------
// attn_pv: recompute S per tile, P = exp(S-m)/l, out += V.P^T.
// v is now bf16. grid(4 cgroups of 128, 32 itiles of 32, 16 b), block 256.
// ---------------------------------------------------------------------------
__global__ __launch_bounds__(256) void attn_pv_kernel(
    const float* __restrict__ q, const float* __restrict__ k,
    const unsigned short* __restrict__ v, const float* __restrict__ sm,
    const float* __restrict__ sl, float* __restrict__ out)
{
    const int c0 = blockIdx.x * 128;
    const int i0 = blockIdx.y * 32;
    const int b  = blockIdx.z;

    __shared__ __align__(16) float qT[32][36];
    __shared__ __align__(16) float kT[64][36];
    __shared__ __align__(16) float vT[64][132];
    __shared__ __align__(16) float pT[64][36];

    const int t = threadIdx.x;
    for (int idx = t; idx < 32 * 32; idx += 256) {
        int ii = idx & 31, d = idx >> 5;
        qT[ii][d] = q[((size_t)b * CQD + d) * NN + i0 + ii];
    }
    __syncthreads();

    const int is = t & 31;
    const int jg = t >> 5;

    float qr[32];
    #pragma unroll
    for (int v4 = 0; v4 < 8; ++v4) {
        float4 qv = *(const float4*)&qT[is][v4 * 4];
        qr[v4*4+0] = qv.x; qr[v4*4+1] = qv.y; qr[v4*4+2] = qv.z; qr[v4*4+3] = qv.w;
    }
    const float mr = sm[(size_t)b * NN + i0 + is];
    const float rl = 1.f / sl[(size_t)b * NN + i0 + is];

    float acc[4][4];
    #pragma unroll
    for (int a = 0; a < 4; ++a)
        #pragma unroll
        for (int bb = 0; bb < 4; ++bb) acc[a][bb] = 0.f;

    #pragma unroll 1
    for (int jc = 0; jc < 16; ++jc) {
        const int j0 = jc * 64;
        __syncthreads();
        for (int idx = t; idx < 64 * 32; idx += 256) {
            int jj = idx & 63, d = idx >> 6;
            kT[jj][d] = k[((size_t)b * CQD + d) * NN + j0 + jj];
        }
        // v staging: bf16 -> f32, 4 j's per thread (8B loads, coalesced)
        for (int idx = t; idx < 2048; idx += 256) {
            int jj = (idx & 15) * 4, c = idx >> 4;
            ushort4v vv = *(const ushort4v*)&v[((size_t)b * CCH + c0 + c) * NN + j0 + jj];
            vT[jj + 0][c] = bf2f(vv[0]);
            vT[jj + 1][c] = bf2f(vv[1]);
            vT[jj + 2][c] = bf2f(vv[2]);
            vT[jj + 3][c] = bf2f(vv[3]);
        }
        __syncthreads();
        #pragma unroll
        for (int u = 0; u < 8; ++u) {
            int jj = jg * 8 + u;
            float s = 0.f;
            #pragma unroll
            for (int v4 = 0; v4 < 8; ++v4) {
                float4 kv = *(const float4*)&kT[jj][v4 * 4];
                s += qr[v4*4+0]*kv.x + qr[v4*4+1]*kv.y + qr[v4*4+2]*kv.z + qr[v4*4+3]*kv.w;
            }
            pT[jj][is] = __expf(s - mr) * rl;
        }
        __syncthreads();
        #pragma unroll 4
        for (int jj = 0; jj < 64; ++jj) {
            float4 vv = *(const float4*)&vT[jj][is * 4];
            float4 pp = *(const float4*)&pT[jj][jg * 4];
            acc[0][0] += vv.x * pp.x; acc[0][1] += vv.x * pp.y;
            acc[0][2] += vv.x * pp.z; acc[0][3] += vv.x * pp.w;
            acc[1][0] += vv.y * pp.x; acc[1][1] += vv.y * pp.y;
            acc[1][2] += vv.y * pp.z; acc[1][3] += vv.y * pp.w;
            acc[2][0] += vv.z * pp.x; acc[2][1] += vv.z * pp.y;
            acc[2][2] += vv.z * pp.z; acc[2][3] += vv.z * pp.w;
            acc[3][0] += vv.w * pp.x; acc[3][1] += vv.w * pp.y;
            acc[3][2] += vv.w * pp.z; acc[3][3] += vv.w * pp.w;
        }
    }

    #pragma unroll
    for (int a = 0; a < 4; ++a) {
        float4 ov = make_float4(acc[a][0], acc[a][1], acc[a][2], acc[a][3]);
        *(float4*)&out[((size_t)b * CCH + c0 + is * 4 + a) * NN + i0 + jg * 4] = ov;
    }
}

// ---------------------------------------------------------------------------
extern "C" void kernel_launch(void* const* d_in, const int* in_sizes, int n_in,
                              void* d_out, int out_size, void* d_ws, size_t ws_size,
                              hipStream_t stream) {
    const float* x  = (const float*)d_in[0];
    const float* y  = (const float*)d_in[1];
    const float* wq = (const float*)d_in[2];
    const float* bq = (const float*)d_in[3];
    const float* wk = (const float*)d_in[4];
    const float* bk = (const float*)d_in[5];
    const float* wv = (const float*)d_in[6];
    const float* bv = (const float*)d_in[7];
    float* out = (float*)d_out;

    // workspace layout: q(2MB) k(2MB) sm sl | v bf16(16.8MB) ybf(16.8MB) wvb(4.7MB)
    float* ws  = (float*)d_ws;
    float* qb  = ws;
    float* kb  = qb + (size_t)BB * CQD * NN;
    float* smb = kb + (size_t)BB * CQD * NN;
    float* slb = smb + (size_t)BB * NN;
    unsigned short* vb  = (unsigned short*)(slb + (size_t)BB * NN);
    unsigned short* ybf = vb + (size_t)BB * CCH * NN;
    unsigned short* wvb = ybf + (size_t)BB * NN * CCH;

    prep_y_kernel<<<dim3(HH, BB), 256, 0, stream>>>(y, ybf);
    prep_w_kernel<<<dim3(512), 256, 0, stream>>>(wv, wvb);
    conv_qk_kernel<<<dim3(8, 2, BB), 256, 0, stream>>>(x, y, wq, bq, wk, bk, qb, kb);
    conv_v_mfma_kernel<<<dim3(4, 8, BB), 256, 0, stream>>>(ybf, wvb, bv, vb);
    stats_kernel<<<dim3(16, BB), 256, 0, stream>>>(qb, kb, smb, slb);
    attn_pv_kernel<<<dim3(4, 32, BB), 256, 0, stream>>>(qb, kb, vb, smb, slb, out);
}

// Round 4
// 625.493 us; speedup vs baseline: 3.9351x; 1.7059x over previous
//
#include <hip/hip_runtime.h>

// Problem constants
#define BB 16
#define CCH 512
#define CQD 32
#define HH 32
#define WW 32
#define NN 1024

typedef __attribute__((ext_vector_type(8))) _Float16 half8;
typedef __attribute__((ext_vector_type(4))) _Float16 half4;
typedef __attribute__((ext_vector_type(4))) float f32x4;

// ---------------------------------------------------------------------------
// prep_y: y[b][ci][h][w] fp32 -> yh[b][h][w][ci] fp16 (ci contiguous)
// ---------------------------------------------------------------------------
__global__ __launch_bounds__(256) void prep_y_kernel(
    const float* __restrict__ y, _Float16* __restrict__ yh)
{
    const int h = blockIdx.x, b = blockIdx.y;
    __shared__ float X[64][33];
    const int t = threadIdx.x;
    for (int ci0 = 0; ci0 < CCH; ci0 += 64) {
        __syncthreads();
        #pragma unroll
        for (int i = 0; i < 8; ++i) {
            int ci = i * 8 + (t >> 5), w = t & 31;
            X[ci][w] = y[((size_t)(b * CCH + ci0 + ci) * HH + h) * WW + w];
        }
        __syncthreads();
        int w = t >> 3, g = t & 7;
        half8 o;
        #pragma unroll
        for (int u = 0; u < 8; ++u) o[u] = (_Float16)X[g * 8 + u][w];
        *(half8*)&yh[(((size_t)b * HH + h) * WW + w) * CCH + ci0 + g * 8] = o;
    }
}

// ---------------------------------------------------------------------------
// prep_w: wv[co][ci][3][3] fp32 -> wvh[co][tap*512+ci] fp16
// ---------------------------------------------------------------------------
__global__ __launch_bounds__(256) void prep_w_kernel(
    const float* __restrict__ wv, _Float16* __restrict__ wvh)
{
    const int co = blockIdx.x;
    for (int idx = threadIdx.x; idx < 4608; idx += 256) {
        int tap = idx / 512, ci = idx - tap * 512;
        wvh[(size_t)co * 4608 + idx] = (_Float16)wv[(size_t)co * 4608 + ci * 9 + tap];
    }
}

// ---------------------------------------------------------------------------
// conv_v_mfma: implicit-GEMM 3x3 conv via fp16 MFMA.
// Block: 64 co x 256 px. 4 waves, each 64co x 64px (4x4 frags).
// grid(4 pxtiles, 8 cotiles, 16 b). Output v fp16 [b][co][px].
// ---------------------------------------------------------------------------
__global__ __launch_bounds__(256, 2) void conv_v_mfma_kernel(
    const _Float16* __restrict__ yh,    // [b][h][w][ci]
    const _Float16* __restrict__ wvh,   // [co][tap*512+ci]
    const float* __restrict__ bvb,
    _Float16* __restrict__ vout)        // fp16 [b][co][px]
{
    const int pt  = blockIdx.x;
    const int co0 = blockIdx.y * 64;
    const int b   = blockIdx.z;

    __shared__ _Float16 Wl[64 * 296];
    __shared__ _Float16 Yl[10 * 34 * 40];

    const int t    = threadIdx.x;
    const int lane = t & 63;
    const int wv4  = t >> 6;
    const int l15  = lane & 15;
    const int kg   = lane >> 4;

    f32x4 acc[4][4];
    #pragma unroll
    for (int m = 0; m < 4; ++m)
        #pragma unroll
        for (int n = 0; n < 4; ++n) {
            f32x4 z = {0.f, 0.f, 0.f, 0.f};
            acc[m][n] = z;
        }

    const int r0 = pt * 8;
    int bbase[4];
    #pragma unroll
    for (int n = 0; n < 4; ++n) {
        int pxl = wv4 * 64 + n * 16 + l15;
        int rl = pxl >> 5, cl = pxl & 31;
        bbase[n] = (rl * 34 + cl) * 40 + kg * 8;
    }
    int abase[4];
    #pragma unroll
    for (int m = 0; m < 4; ++m)
        abase[m] = (m * 16 + l15) * 296 + kg * 8;

    #pragma unroll 1
    for (int ci0 = 0; ci0 < CCH; ci0 += 32) {
        __syncthreads();
        #pragma unroll
        for (int i = 0; i < 9; ++i) {
            int idx = t + i * 256;
            int c = idx / 36, rem = idx - c * 36;
            int tap = rem >> 2, part = rem & 3;
            half8 v = *(const half8*)&wvh[(size_t)(co0 + c) * 4608 + tap * 512 + ci0 + part * 8];
            *(half8*)&Wl[c * 296 + tap * 32 + part * 8] = v;
        }
        for (int idx = t; idx < 1360; idx += 256) {
            int hw = idx >> 2, part = idx & 3;
            int r = hw / 34, c = hw - r * 34;
            int gh = r0 - 1 + r, gw = c - 1;
            half8 v;
            if (gh >= 0 && gh < HH && gw >= 0 && gw < WW) {
                v = *(const half8*)&yh[(((size_t)b * HH + gh) * WW + gw) * CCH + ci0 + part * 8];
            } else {
                #pragma unroll
                for (int u = 0; u < 8; ++u) v[u] = (_Float16)0.f;
            }
            *(half8*)&Yl[(r * 34 + c) * 40 + part * 8] = v;
        }
        __syncthreads();

        #pragma unroll
        for (int tap = 0; tap < 9; ++tap) {
            const int dh = tap / 3, dw = tap % 3;
            half8 a[4], bf[4];
            #pragma unroll
            for (int m = 0; m < 4; ++m)
                a[m] = *(const half8*)&Wl[abase[m] + tap * 32];
            #pragma unroll
            for (int n = 0; n < 4; ++n)
                bf[n] = *(const half8*)&Yl[bbase[n] + (dh * 34 + dw) * 40];
            #pragma unroll
            for (int m = 0; m < 4; ++m)
                #pragma unroll
                for (int n = 0; n < 4; ++n)
                    acc[m][n] = __builtin_amdgcn_mfma_f32_16x16x32_f16(a[m], bf[n], acc[m][n], 0, 0, 0);
        }
    }

    #pragma unroll
    for (int m = 0; m < 4; ++m) {
        #pragma unroll
        for (int reg = 0; reg < 4; ++reg) {
            int co = co0 + m * 16 + kg * 4 + reg;
            float bias = bvb[co];
            #pragma unroll
            for (int n = 0; n < 4; ++n) {
                int px = pt * 256 + wv4 * 64 + n * 16 + l15;
                vout[((size_t)b * CCH + co) * NN + px] = (_Float16)(acc[m][n][reg] + bias);
            }
        }
    }
}

// ---------------------------------------------------------------------------
// conv_qk: C_out=32 3x3 SAME conv, fp32 compute, fp16 [b][n][d] output.
// grid(8 rowtiles, 2 which, 16 b), block 256.
// ---------------------------------------------------------------------------
__global__ __launch_bounds__(256) void conv_qk_kernel(
    const float* __restrict__ x, const float* __restrict__ y,
    const float* __restrict__ wq, const float* __restrict__ bq,
    const float* __restrict__ wk, const float* __restrict__ bk,
    _Float16* __restrict__ qh, _Float16* __restrict__ kh)
{
    const int rt    = blockIdx.x;
    const int which = blockIdx.y;
    const int b     = blockIdx.z;
    const float* in   = which ? y  : x;
    const float* wgt  = which ? wk : wq;
    const float* bias = which ? bk : bq;
    _Float16* out = which ? kh : qh;

    __shared__ __align__(16) float Wl[32][289];
    __shared__ __align__(16) float Xl[32][6][36];

    const int t    = threadIdx.x;
    const int co   = t & 31;
    const int grp  = t >> 5;
    const int rr   = grp >> 1;
    const int col0 = (grp & 1) * 16;

    float acc[16];
    {
        float bv = bias[co];
        #pragma unroll
        for (int i = 0; i < 16; ++i) acc[i] = bv;
    }

    #pragma unroll 1
    for (int ci0 = 0; ci0 < CCH; ci0 += 32) {
        __syncthreads();
        for (int idx = t; idx < 32 * 288; idx += 256) {
            int c = idx / 288, r = idx - c * 288;
            Wl[c][r] = wgt[c * 4608 + ci0 * 9 + r];
        }
        for (int idx = t; idx < 32 * 216; idx += 256) {
            int ci = idx / 216, rem = idx - ci * 216;
            int r = rem / 36, c = rem - r * 36;
            int gr = rt * 4 - 1 + r;
            int gc = c - 1;
            float v = 0.f;
            if (gr >= 0 && gr < HH && gc >= 0 && gc < WW)
                v = in[((size_t)(b * CCH + ci0 + ci) * HH + gr) * WW + gc];
            Xl[ci][r][c] = v;
        }
        __syncthreads();

        #pragma unroll 1
        for (int ci = 0; ci < 32; ++ci) {
            #pragma unroll
            for (int dh = 0; dh < 3; ++dh) {
                float xr[20];
                #pragma unroll
                for (int v4 = 0; v4 < 5; ++v4) {
                    float4 xv = *(const float4*)&Xl[ci][rr + dh][col0 + v4 * 4];
                    xr[v4*4+0] = xv.x; xr[v4*4+1] = xv.y;
                    xr[v4*4+2] = xv.z; xr[v4*4+3] = xv.w;
                }
                float w0 = Wl[co][ci * 9 + dh * 3 + 0];
                float w1 = Wl[co][ci * 9 + dh * 3 + 1];
                float w2 = Wl[co][ci * 9 + dh * 3 + 2];
                #pragma unroll
                for (int cc = 0; cc < 16; ++cc)
                    acc[cc] += w0 * xr[cc] + w1 * xr[cc + 1] + w2 * xr[cc + 2];
            }
        }
    }

    const int pxbase = (rt * 4 + rr) * WW + col0;
    #pragma unroll
    for (int cc = 0; cc < 16; ++cc)
        out[((size_t)b * NN + pxbase + cc) * CQD + co] = (_Float16)acc[cc];
}

// ---------------------------------------------------------------------------
// stats: per (b,i) softmax row stats from fp16 q,k [b][n][d].
// grid(16 itiles, 16 b), block 256.
// ---------------------------------------------------------------------------
__global__ __launch_bounds__(256) void stats_kernel(
    const _Float16* __restrict__ qh, const _Float16* __restrict__ kh,
    float* __restrict__ sm, float* __restrict__ sl)
{
    const int i0 = blockIdx.x * 64;
    const int b  = blockIdx.y;

    __shared__ __align__(16) float qT[64][36];
    __shared__ __align__(16) float kT[128][36];
    __shared__ float redm[4][64];
    __shared__ float redl[4][64];

    const int t = threadIdx.x;
    {
        int ii = t >> 2, part = t & 3;
        half8 qv = *(const half8*)&qh[((size_t)b * NN + i0 + ii) * CQD + part * 8];
        #pragma unroll
        for (int u = 0; u < 8; ++u) qT[ii][part * 8 + u] = (float)qv[u];
    }
    __syncthreads();

    const int il = t & 63, js = t >> 6;
    float qr[32];
    #pragma unroll
    for (int v4 = 0; v4 < 8; ++v4) {
        float4 qv = *(const float4*)&qT[il][v4 * 4];
        qr[v4*4+0] = qv.x; qr[v4*4+1] = qv.y; qr[v4*4+2] = qv.z; qr[v4*4+3] = qv.w;
    }

    float m = -1e30f, l = 0.f;
    #pragma unroll 1
    for (int jc = 0; jc < 8; ++jc) {
        __syncthreads();
        #pragma unroll
        for (int r = 0; r < 2; ++r) {
            int idx = t + r * 256;
            int jj = idx >> 2, part = idx & 3;
            half8 kv = *(const half8*)&kh[((size_t)b * NN + jc * 128 + jj) * CQD + part * 8];
            #pragma unroll
            for (int u = 0; u < 8; ++u) kT[jj][part * 8 + u] = (float)kv[u];
        }
        __syncthreads();
        #pragma unroll 1
        for (int u = 0; u < 32; ++u) {
            int jj = js * 32 + u;
            float s = 0.f;
            #pragma unroll
            for (int v4 = 0; v4 < 8; ++v4) {
                float4 kv = *(const float4*)&kT[jj][v4 * 4];
                s += qr[v4*4+0]*kv.x + qr[v4*4+1]*kv.y + qr[v4*4+2]*kv.z + qr[v4*4+3]*kv.w;
            }
            if (s > m) { l = l * __expf(m - s) + 1.f; m = s; }
            else       { l += __expf(s - m); }
        }
    }
    redm[js][il] = m;
    redl[js][il] = l;
    __syncthreads();
    if (t < 64) {
        float M = redm[0][t];
        #pragma unroll
        for (int u = 1; u < 4; ++u) M = fmaxf(M, redm[u][t]);
        float L = 0.f;
        #pragma unroll
        for (int u = 0; u < 4; ++u) L += redl[u][t] * __expf(redm[u][t] - M);
        sm[(size_t)b * NN + i0 + t] = M;
        sl[(size_t)b * NN + i0 + t] = L;
    }
}

// ---------------------------------------------------------------------------
// attn_mfma: S = K.Q^T via MFMA (swapped), P = exp(S-m)/l packed fp16 to LDS,
// out = V.P via MFMA. Block: 128 c x 32 i, 4 waves (wave = 32c x 32i).
// grid(4 ctiles, 32 itiles, 16 b), block 256.
// ---------------------------------------------------------------------------
__global__ __launch_bounds__(256) void attn_mfma_kernel(
    const _Float16* __restrict__ qh,  // [b][i][d]
    const _Float16* __restrict__ kh,  // [b][j][d]
    const _Float16* __restrict__ v,   // [b][c][j]
    const float* __restrict__ sm, const float* __restrict__ sl,
    float* __restrict__ out)
{
    const int c0 = blockIdx.x * 128;
    const int i0 = blockIdx.y * 32;
    const int b  = blockIdx.z;

    __shared__ _Float16 Kl[64 * 40];    // [j][d+8pad]
    __shared__ _Float16 Vl[128 * 72];   // [c][j+8pad]
    __shared__ _Float16 Pl[32 * 72];    // [i][j+8pad]

    const int t    = threadIdx.x;
    const int lane = t & 63;
    const int w    = t >> 6;
    const int l15  = lane & 15;
    const int kg   = lane >> 4;

    half8 qb[2];
    float mr[2], rl[2];
    #pragma unroll
    for (int n = 0; n < 2; ++n) {
        int i = i0 + n * 16 + l15;
        qb[n] = *(const half8*)&qh[((size_t)b * NN + i) * CQD + kg * 8];
        mr[n] = sm[(size_t)b * NN + i];
        rl[n] = 1.f / sl[(size_t)b * NN + i];
    }

    f32x4 acc[2][2];
    #pragma unroll
    for (int m = 0; m < 2; ++m)
        #pragma unroll
        for (int n = 0; n < 2; ++n) {
            f32x4 z = {0.f, 0.f, 0.f, 0.f};
            acc[m][n] = z;
        }

    #pragma unroll 1
    for (int jt = 0; jt < 16; ++jt) {
        const int j0 = jt * 64;
        __syncthreads();
        {
            int j = t >> 2, part = t & 3;
            *(half8*)&Kl[j * 40 + part * 8] =
                *(const half8*)&kh[((size_t)b * NN + j0 + j) * CQD + part * 8];
        }
        #pragma unroll
        for (int r = 0; r < 4; ++r) {
            int idx = t + r * 256;
            int c = idx >> 3, jp = idx & 7;
            *(half8*)&Vl[c * 72 + jp * 8] =
                *(const half8*)&v[((size_t)b * CCH + c0 + c) * NN + j0 + jp * 8];
        }
        __syncthreads();

        // S phase (swapped): D[row=j=kg*4+reg][col=i=n*16+l15]
        {
            half8 ak = *(const half8*)&Kl[(w * 16 + l15) * 40 + kg * 8];
            #pragma unroll
            for (int n = 0; n < 2; ++n) {
                f32x4 s = {0.f, 0.f, 0.f, 0.f};
                s = __builtin_amdgcn_mfma_f32_16x16x32_f16(ak, qb[n], s, 0, 0, 0);
                half4 p4;
                #pragma unroll
                for (int reg = 0; reg < 4; ++reg)
                    p4[reg] = (_Float16)(__expf(s[reg] - mr[n]) * rl[n]);
                *(half4*)&Pl[(n * 16 + l15) * 72 + w * 16 + kg * 4] = p4;
            }
        }
        __syncthreads();

        // PV: out[c][i] += V[c][j] * P[j][i], K=64 (2 x K32)
        #pragma unroll
        for (int ks = 0; ks < 2; ++ks) {
            half8 pb[2], va[2];
            #pragma unroll
            for (int n = 0; n < 2; ++n)
                pb[n] = *(const half8*)&Pl[(n * 16 + l15) * 72 + ks * 32 + kg * 8];
            #pragma unroll
            for (int m = 0; m < 2; ++m)
                va[m] = *(const half8*)&Vl[(w * 32 + m * 16 + l15) * 72 + ks * 32 + kg * 8];
            #pragma unroll
            for (int m = 0; m < 2; ++m)
                #pragma unroll
                for (int n = 0; n < 2; ++n)
                    acc[m][n] = __builtin_amdgcn_mfma_f32_16x16x32_f16(va[m], pb[n], acc[m][n], 0, 0, 0);
        }
    }

    #pragma unroll
    for (int m = 0; m < 2; ++m)
        #pragma unroll
        for (int n = 0; n < 2; ++n)
            #pragma unroll
            for (int reg = 0; reg < 4; ++reg) {
                int c = c0 + w * 32 + m * 16 + kg * 4 + reg;
                out[((size_t)b * CCH + c) * NN + i0 + n * 16 + l15] = acc[m][n][reg];
            }
}

// ---------------------------------------------------------------------------
extern "C" void kernel_launch(void* const* d_in, const int* in_sizes, int n_in,
                              void* d_out, int out_size, void* d_ws, size_t ws_size,
                              hipStream_t stream) {
    const float* x  = (const float*)d_in[0];
    const float* y  = (const float*)d_in[1];
    const float* wq = (const float*)d_in[2];
    const float* bq = (const float*)d_in[3];
    const float* wk = (const float*)d_in[4];
    const float* bk = (const float*)d_in[5];
    const float* wv = (const float*)d_in[6];
    const float* bv = (const float*)d_in[7];
    float* out = (float*)d_out;

    // ws layout: qh(1MB) kh(1MB) | sm(64KB) sl(64KB) | v(16.8MB) yh(16.8MB) wvh(4.7MB)
    _Float16* qhb = (_Float16*)d_ws;
    _Float16* khb = qhb + (size_t)BB * NN * CQD;
    float* smb = (float*)(khb + (size_t)BB * NN * CQD);
    float* slb = smb + (size_t)BB * NN;
    _Float16* vb  = (_Float16*)(slb + (size_t)BB * NN);
    _Float16* yhb = vb + (size_t)BB * CCH * NN;
    _Float16* wvh = yhb + (size_t)BB * NN * CCH;

    prep_y_kernel<<<dim3(HH, BB), 256, 0, stream>>>(y, yhb);
    prep_w_kernel<<<dim3(512), 256, 0, stream>>>(wv, wvh);
    conv_qk_kernel<<<dim3(8, 2, BB), 256, 0, stream>>>(x, y, wq, bq, wk, bk, qhb, khb);
    conv_v_mfma_kernel<<<dim3(4, 8, BB), 256, 0, stream>>>(yhb, wvh, bv, vb);
    stats_kernel<<<dim3(16, BB), 256, 0, stream>>>(qhb, khb, smb, slb);
    attn_mfma_kernel<<<dim3(4, 32, BB), 256, 0, stream>>>(qhb, khb, vb, smb, slb, out);
}

// Round 5
// 301.117 us; speedup vs baseline: 8.1741x; 2.0772x over previous
//
#include <hip/hip_runtime.h>

// Problem constants
#define BB 16
#define CCH 512
#define CQD 32
#define HH 32
#define WW 32
#define NN 1024

typedef __attribute__((ext_vector_type(8))) _Float16 half8;
typedef __attribute__((ext_vector_type(4))) _Float16 half4;
typedef __attribute__((ext_vector_type(4))) float f32x4;

// ---------------------------------------------------------------------------
// prep_img: img[b][ci][h][w] fp32 -> imgh[b][h][w][ci] fp16 (ci contiguous)
// grid(32 h, 16 b), block 256
// ---------------------------------------------------------------------------
__global__ __launch_bounds__(256) void prep_img_kernel(
    const float* __restrict__ img, _Float16* __restrict__ imgh)
{
    const int h = blockIdx.x, b = blockIdx.y;
    __shared__ float X[64][33];
    const int t = threadIdx.x;
    for (int ci0 = 0; ci0 < CCH; ci0 += 64) {
        __syncthreads();
        #pragma unroll
        for (int i = 0; i < 8; ++i) {
            int ci = i * 8 + (t >> 5), w = t & 31;
            X[ci][w] = img[((size_t)(b * CCH + ci0 + ci) * HH + h) * WW + w];
        }
        __syncthreads();
        int w = t >> 3, g = t & 7;
        half8 o;
        #pragma unroll
        for (int u = 0; u < 8; ++u) o[u] = (_Float16)X[g * 8 + u][w];
        *(half8*)&imgh[(((size_t)b * HH + h) * WW + w) * CCH + ci0 + g * 8] = o;
    }
}

// ---------------------------------------------------------------------------
// prep_w: wv[co][ci][3][3] fp32 -> wvh[co][tap*512+ci] fp16. grid(512).
// ---------------------------------------------------------------------------
__global__ __launch_bounds__(256) void prep_w_kernel(
    const float* __restrict__ wv, _Float16* __restrict__ wvh)
{
    const int co = blockIdx.x;
    for (int idx = threadIdx.x; idx < 4608; idx += 256) {
        int tap = idx / 512, ci = idx - tap * 512;
        wvh[(size_t)co * 4608 + idx] = (_Float16)wv[(size_t)co * 4608 + ci * 9 + tap];
    }
}

// ---------------------------------------------------------------------------
// prep_wqk: wq,wk [32][512][3][3] -> wqkh[which*32+co][tap*512+ci]. grid(64).
// ---------------------------------------------------------------------------
__global__ __launch_bounds__(256) void prep_wqk_kernel(
    const float* __restrict__ wq, const float* __restrict__ wk,
    _Float16* __restrict__ wqkh)
{
    const int co = blockIdx.x;                 // 0..63
    const float* src = (co < 32) ? wq : wk;
    const int c = co & 31;
    for (int idx = threadIdx.x; idx < 4608; idx += 256) {
        int tap = idx / 512, ci = idx - tap * 512;
        wqkh[(size_t)co * 4608 + idx] = (_Float16)src[(size_t)c * 4608 + ci * 9 + tap];
    }
}

// ---------------------------------------------------------------------------
// conv_v_mfma: implicit-GEMM 3x3 conv via fp16 MFMA (unchanged from R4).
// ---------------------------------------------------------------------------
__global__ __launch_bounds__(256, 2) void conv_v_mfma_kernel(
    const _Float16* __restrict__ yh,    // [b][h][w][ci]
    const _Float16* __restrict__ wvh,   // [co][tap*512+ci]
    const float* __restrict__ bvb,
    _Float16* __restrict__ vout)        // fp16 [b][co][px]
{
    const int pt  = blockIdx.x;
    const int co0 = blockIdx.y * 64;
    const int b   = blockIdx.z;

    __shared__ _Float16 Wl[64 * 296];
    __shared__ _Float16 Yl[10 * 34 * 40];

    const int t    = threadIdx.x;
    const int lane = t & 63;
    const int wv4  = t >> 6;
    const int l15  = lane & 15;
    const int kg   = lane >> 4;

    f32x4 acc[4][4];
    #pragma unroll
    for (int m = 0; m < 4; ++m)
        #pragma unroll
        for (int n = 0; n < 4; ++n) {
            f32x4 z = {0.f, 0.f, 0.f, 0.f};
            acc[m][n] = z;
        }

    const int r0 = pt * 8;
    int bbase[4];
    #pragma unroll
    for (int n = 0; n < 4; ++n) {
        int pxl = wv4 * 64 + n * 16 + l15;
        int rl = pxl >> 5, cl = pxl & 31;
        bbase[n] = (rl * 34 + cl) * 40 + kg * 8;
    }
    int abase[4];
    #pragma unroll
    for (int m = 0; m < 4; ++m)
        abase[m] = (m * 16 + l15) * 296 + kg * 8;

    #pragma unroll 1
    for (int ci0 = 0; ci0 < CCH; ci0 += 32) {
        __syncthreads();
        #pragma unroll
        for (int i = 0; i < 9; ++i) {
            int idx = t + i * 256;
            int c = idx / 36, rem = idx - c * 36;
            int tap = rem >> 2, part = rem & 3;
            half8 v = *(const half8*)&wvh[(size_t)(co0 + c) * 4608 + tap * 512 + ci0 + part * 8];
            *(half8*)&Wl[c * 296 + tap * 32 + part * 8] = v;
        }
        for (int idx = t; idx < 1360; idx += 256) {
            int hw = idx >> 2, part = idx & 3;
            int r = hw / 34, c = hw - r * 34;
            int gh = r0 - 1 + r, gw = c - 1;
            half8 v;
            if (gh >= 0 && gh < HH && gw >= 0 && gw < WW) {
                v = *(const half8*)&yh[(((size_t)b * HH + gh) * WW + gw) * CCH + ci0 + part * 8];
            } else {
                #pragma unroll
                for (int u = 0; u < 8; ++u) v[u] = (_Float16)0.f;
            }
            *(half8*)&Yl[(r * 34 + c) * 40 + part * 8] = v;
        }
        __syncthreads();

        #pragma unroll
        for (int tap = 0; tap < 9; ++tap) {
            const int dh = tap / 3, dw = tap % 3;
            half8 a[4], bf[4];
            #pragma unroll
            for (int m = 0; m < 4; ++m)
                a[m] = *(const half8*)&Wl[abase[m] + tap * 32];
            #pragma unroll
            for (int n = 0; n < 4; ++n)
                bf[n] = *(const half8*)&Yl[bbase[n] + (dh * 34 + dw) * 40];
            #pragma unroll
            for (int m = 0; m < 4; ++m)
                #pragma unroll
                for (int n = 0; n < 4; ++n)
                    acc[m][n] = __builtin_amdgcn_mfma_f32_16x16x32_f16(a[m], bf[n], acc[m][n], 0, 0, 0);
        }
    }

    #pragma unroll
    for (int m = 0; m < 4; ++m) {
        #pragma unroll
        for (int reg = 0; reg < 4; ++reg) {
            int co = co0 + m * 16 + kg * 4 + reg;
            float bias = bvb[co];
            #pragma unroll
            for (int n = 0; n < 4; ++n) {
                int px = pt * 256 + wv4 * 64 + n * 16 + l15;
                vout[((size_t)b * CCH + co) * NN + px] = (_Float16)(acc[m][n][reg] + bias);
            }
        }
    }
}

// ---------------------------------------------------------------------------
// conv_qk_mfma: 32-co 3x3 conv via fp16 MFMA, writes fp16 [b][px][d].
// Block: 32 co x 128 px (4 image rows). 4 waves, each 32co x 32px (2x2 frags).
// grid(8 pxtiles, 2 which, 16 b), block 256.
// ---------------------------------------------------------------------------
__global__ __launch_bounds__(256, 2) void conv_qk_mfma_kernel(
    const _Float16* __restrict__ xh,    // [b][h][w][ci]
    const _Float16* __restrict__ yh,    // [b][h][w][ci]
    const _Float16* __restrict__ wqkh,  // [which*32+co][tap*512+ci]
    const float* __restrict__ bq, const float* __restrict__ bk,
    _Float16* __restrict__ qh, _Float16* __restrict__ kh)
{
    const int pt    = blockIdx.x;        // image rows pt*4 .. pt*4+3
    const int which = blockIdx.y;
    const int b     = blockIdx.z;
    const _Float16* in  = which ? yh : xh;
    const float* bias   = which ? bk : bq;
    _Float16* out       = which ? kh : qh;

    __shared__ _Float16 Wl[32 * 296];       // [co][9tap*32ci + 8pad]
    __shared__ _Float16 Xl[6 * 34 * 40];    // [row][col][32ci + 8pad]

    const int t    = threadIdx.x;
    const int lane = t & 63;
    const int w    = t >> 6;
    const int l15  = lane & 15;
    const int kg   = lane >> 4;

    f32x4 acc[2][2];
    #pragma unroll
    for (int m = 0; m < 2; ++m)
        #pragma unroll
        for (int n = 0; n < 2; ++n) {
            f32x4 z = {0.f, 0.f, 0.f, 0.f};
            acc[m][n] = z;
        }

    const int r0 = pt * 4;
    int bbase[2];
    #pragma unroll
    for (int n = 0; n < 2; ++n) {
        int pxl = w * 32 + n * 16 + l15;       // 0..127 local px
        int rl = pxl >> 5, cl = pxl & 31;
        bbase[n] = (rl * 34 + cl) * 40 + kg * 8;
    }
    int abase[2];
    #pragma unroll
    for (int m = 0; m < 2; ++m)
        abase[m] = (m * 16 + l15) * 296 + kg * 8;

    #pragma unroll 1
    for (int ci0 = 0; ci0 < CCH; ci0 += 32) {
        __syncthreads();
        // stage W: 32co x 9tap x 32ci = 1152 16B ops
        for (int idx = t; idx < 1152; idx += 256) {
            int c = idx / 36, rem = idx - c * 36;
            int tap = rem >> 2, part = rem & 3;
            half8 v = *(const half8*)&wqkh[(size_t)(which * 32 + c) * 4608 + tap * 512 + ci0 + part * 8];
            *(half8*)&Wl[c * 296 + tap * 32 + part * 8] = v;
        }
        // stage X: 6 rows x 34 cols x 32ci = 816 16B ops, zero halo
        for (int idx = t; idx < 816; idx += 256) {
            int hw = idx >> 2, part = idx & 3;
            int r = hw / 34, c = hw - r * 34;
            int gh = r0 - 1 + r, gw = c - 1;
            half8 v;
            if (gh >= 0 && gh < HH && gw >= 0 && gw < WW) {
                v = *(const half8*)&in[(((size_t)b * HH + gh) * WW + gw) * CCH + ci0 + part * 8];
            } else {
                #pragma unroll
                for (int u = 0; u < 8; ++u) v[u] = (_Float16)0.f;
            }
            *(half8*)&Xl[(r * 34 + c) * 40 + part * 8] = v;
        }
        __syncthreads();

        #pragma unroll
        for (int tap = 0; tap < 9; ++tap) {
            const int dh = tap / 3, dw = tap % 3;
            half8 a[2], bfr[2];
            #pragma unroll
            for (int m = 0; m < 2; ++m)
                a[m] = *(const half8*)&Wl[abase[m] + tap * 32];
            #pragma unroll
            for (int n = 0; n < 2; ++n)
                bfr[n] = *(const half8*)&Xl[bbase[n] + (dh * 34 + dw) * 40];
            #pragma unroll
            for (int m = 0; m < 2; ++m)
                #pragma unroll
                for (int n = 0; n < 2; ++n)
                    acc[m][n] = __builtin_amdgcn_mfma_f32_16x16x32_f16(a[m], bfr[n], acc[m][n], 0, 0, 0);
        }
    }

    // epilogue: D[row=co=m*16+kg*4+reg][col=px=n*16+l15]; 4 consecutive co/lane
    #pragma unroll
    for (int n = 0; n < 2; ++n) {
        int px = pt * 128 + w * 32 + n * 16 + l15;
        #pragma unroll
        for (int m = 0; m < 2; ++m) {
            half4 p4;
            #pragma unroll
            for (int reg = 0; reg < 4; ++reg)
                p4[reg] = (_Float16)(acc[m][n][reg] + bias[m * 16 + kg * 4 + reg]);
            *(half4*)&out[((size_t)b * NN + px) * CQD + m * 16 + kg * 4] = p4;
        }
    }
}

// ---------------------------------------------------------------------------
// stats: per (b,i) softmax row stats from fp16 q,k [b][n][d].
// grid(16 itiles, 16 b), block 256.
// ---------------------------------------------------------------------------
__global__ __launch_bounds__(256) void stats_kernel(
    const _Float16* __restrict__ qh, const _Float16* __restrict__ kh,
    float* __restrict__ sm, float* __restrict__ sl)
{
    const int i0 = blockIdx.x * 64;
    const int b  = blockIdx.y;

    __shared__ __align__(16) float qT[64][36];
    __shared__ __align__(16) float kT[128][36];
    __shared__ float redm[4][64];
    __shared__ float redl[4][64];

    const int t = threadIdx.x;
    {
        int ii = t >> 2, part = t & 3;
        half8 qv = *(const half8*)&qh[((size_t)b * NN + i0 + ii) * CQD + part * 8];
        #pragma unroll
        for (int u = 0; u < 8; ++u) qT[ii][part * 8 + u] = (float)qv[u];
    }
    __syncthreads();

    const int il = t & 63, js = t >> 6;
    float qr[32];
    #pragma unroll
    for (int v4 = 0; v4 < 8; ++v4) {
        float4 qv = *(const float4*)&qT[il][v4 * 4];
        qr[v4*4+0] = qv.x; qr[v4*4+1] = qv.y; qr[v4*4+2] = qv.z; qr[v4*4+3] = qv.w;
    }

    float m = -1e30f, l = 0.f;
    #pragma unroll 1
    for (int jc = 0; jc < 8; ++jc) {
        __syncthreads();
        #pragma unroll
        for (int r = 0; r < 2; ++r) {
            int idx = t + r * 256;
            int jj = idx >> 2, part = idx & 3;
            half8 kv = *(const half8*)&kh[((size_t)b * NN + jc * 128 + jj) * CQD + part * 8];
            #pragma unroll
            for (int u = 0; u < 8; ++u) kT[jj][part * 8 + u] = (float)kv[u];
        }
        __syncthreads();
        #pragma unroll 1
        for (int u = 0; u < 32; ++u) {
            int jj = js * 32 + u;
            float s = 0.f;
            #pragma unroll
            for (int v4 = 0; v4 < 8; ++v4) {
                float4 kv = *(const float4*)&kT[jj][v4 * 4];
                s += qr[v4*4+0]*kv.x + qr[v4*4+1]*kv.y + qr[v4*4+2]*kv.z + qr[v4*4+3]*kv.w;
            }
            if (s > m) { l = l * __expf(m - s) + 1.f; m = s; }
            else       { l += __expf(s - m); }
        }
    }
    redm[js][il] = m;
    redl[js][il] = l;
    __syncthreads();
    if (t < 64) {
        float M = redm[0][t];
        #pragma unroll
        for (int u = 1; u < 4; ++u) M = fmaxf(M, redm[u][t]);
        float L = 0.f;
        #pragma unroll
        for (int u = 0; u < 4; ++u) L += redl[u][t] * __expf(redm[u][t] - M);
        sm[(size_t)b * NN + i0 + t] = M;
        sl[(size_t)b * NN + i0 + t] = L;
    }
}

// ---------------------------------------------------------------------------
// attn_mfma: S = K.Q^T via MFMA (swapped), P = exp(S-m)/l packed fp16 to LDS,
// out = V.P via MFMA. Block: 128 c x 32 i, 4 waves (wave = 32c x 32i).
// grid(4 ctiles, 32 itiles, 16 b), block 256.
// ---------------------------------------------------------------------------
__global__ __launch_bounds__(256) void attn_mfma_kernel(
    const _Float16* __restrict__ qh,  // [b][i][d]
    const _Float16* __restrict__ kh,  // [b][j][d]
    const _Float16* __restrict__ v,   // [b][c][j]
    const float* __restrict__ sm, const float* __restrict__ sl,
    float* __restrict__ out)
{
    const int c0 = blockIdx.x * 128;
    const int i0 = blockIdx.y * 32;
    const int b  = blockIdx.z;

    __shared__ _Float16 Kl[64 * 40];    // [j][d+8pad]
    __shared__ _Float16 Vl[128 * 72];   // [c][j+8pad]
    __shared__ _Float16 Pl[32 * 72];    // [i][j+8pad]

    const int t    = threadIdx.x;
    const int lane = t & 63;
    const int w    = t >> 6;
    const int l15  = lane & 15;
    const int kg   = lane >> 4;

    half8 qb[2];
    float mr[2], rl[2];
    #pragma unroll
    for (int n = 0; n < 2; ++n) {
        int i = i0 + n * 16 + l15;
        qb[n] = *(const half8*)&qh[((size_t)b * NN + i) * CQD + kg * 8];
        mr[n] = sm[(size_t)b * NN + i];
        rl[n] = 1.f / sl[(size_t)b * NN + i];
    }

    f32x4 acc[2][2];
    #pragma unroll
    for (int m = 0; m < 2; ++m)
        #pragma unroll
        for (int n = 0; n < 2; ++n) {
            f32x4 z = {0.f, 0.f, 0.f, 0.f};
            acc[m][n] = z;
        }

    #pragma unroll 1
    for (int jt = 0; jt < 16; ++jt) {
        const int j0 = jt * 64;
        __syncthreads();
        {
            int j = t >> 2, part = t & 3;
            *(half8*)&Kl[j * 40 + part * 8] =
                *(const half8*)&kh[((size_t)b * NN + j0 + j) * CQD + part * 8];
        }
        #pragma unroll
        for (int r = 0; r < 4; ++r) {
            int idx = t + r * 256;
            int c = idx >> 3, jp = idx & 7;
            *(half8*)&Vl[c * 72 + jp * 8] =
                *(const half8*)&v[((size_t)b * CCH + c0 + c) * NN + j0 + jp * 8];
        }
        __syncthreads();

        // S phase (swapped): D[row=j=kg*4+reg][col=i=n*16+l15]
        {
            half8 ak = *(const half8*)&Kl[(w * 16 + l15) * 40 + kg * 8];
            #pragma unroll
            for (int n = 0; n < 2; ++n) {
                f32x4 s = {0.f, 0.f, 0.f, 0.f};
                s = __builtin_amdgcn_mfma_f32_16x16x32_f16(ak, qb[n], s, 0, 0, 0);
                half4 p4;
                #pragma unroll
                for (int reg = 0; reg < 4; ++reg)
                    p4[reg] = (_Float16)(__expf(s[reg] - mr[n]) * rl[n]);
                *(half4*)&Pl[(n * 16 + l15) * 72 + w * 16 + kg * 4] = p4;
            }
        }
        __syncthreads();

        // PV: out[c][i] += V[c][j] * P[j][i], K=64 (2 x K32)
        #pragma unroll
        for (int ks = 0; ks < 2; ++ks) {
            half8 pb[2], va[2];
            #pragma unroll
            for (int n = 0; n < 2; ++n)
                pb[n] = *(const half8*)&Pl[(n * 16 + l15) * 72 + ks * 32 + kg * 8];
            #pragma unroll
            for (int m = 0; m < 2; ++m)
                va[m] = *(const half8*)&Vl[(w * 32 + m * 16 + l15) * 72 + ks * 32 + kg * 8];
            #pragma unroll
            for (int m = 0; m < 2; ++m)
                #pragma unroll
                for (int n = 0; n < 2; ++n)
                    acc[m][n] = __builtin_amdgcn_mfma_f32_16x16x32_f16(va[m], pb[n], acc[m][n], 0, 0, 0);
        }
    }

    #pragma unroll
    for (int m = 0; m < 2; ++m)
        #pragma unroll
        for (int n = 0; n < 2; ++n)
            #pragma unroll
            for (int reg = 0; reg < 4; ++reg) {
                int c = c0 + w * 32 + m * 16 + kg * 4 + reg;
                out[((size_t)b * CCH + c) * NN + i0 + n * 16 + l15] = acc[m][n][reg];
            }
}

// ---------------------------------------------------------------------------
extern "C" void kernel_launch(void* const* d_in, const int* in_sizes, int n_in,
                              void* d_out, int out_size, void* d_ws, size_t ws_size,
                              hipStream_t stream) {
    const float* x  = (const float*)d_in[0];
    const float* y  = (const float*)d_in[1];
    const float* wq = (const float*)d_in[2];
    const float* bq = (const float*)d_in[3];
    const float* wk = (const float*)d_in[4];
    const float* bk = (const float*)d_in[5];
    const float* wv = (const float*)d_in[6];
    const float* bv = (const float*)d_in[7];
    float* out = (float*)d_out;

    // ws layout: qh(1M) kh(1M) sm/sl(128K) | v(16M) yh(16M) xh(16M) wvh(4.5M) wqkh(0.6M)
    _Float16* qhb = (_Float16*)d_ws;
    _Float16* khb = qhb + (size_t)BB * NN * CQD;
    float* smb = (float*)(khb + (size_t)BB * NN * CQD);
    float* slb = smb + (size_t)BB * NN;
    _Float16* vb   = (_Float16*)(slb + (size_t)BB * NN);
    _Float16* yhb  = vb + (size_t)BB * CCH * NN;
    _Float16* xhb  = yhb + (size_t)BB * NN * CCH;
    _Float16* wvh  = xhb + (size_t)BB * NN * CCH;
    _Float16* wqkh = wvh + (size_t)512 * 4608;

    prep_img_kernel<<<dim3(HH, BB), 256, 0, stream>>>(y, yhb);
    prep_img_kernel<<<dim3(HH, BB), 256, 0, stream>>>(x, xhb);
    prep_w_kernel<<<dim3(512), 256, 0, stream>>>(wv, wvh);
    prep_wqk_kernel<<<dim3(64), 256, 0, stream>>>(wq, wk, wqkh);
    conv_qk_mfma_kernel<<<dim3(8, 2, BB), 256, 0, stream>>>(xhb, yhb, wqkh, bq, bk, qhb, khb);
    conv_v_mfma_kernel<<<dim3(4, 8, BB), 256, 0, stream>>>(yhb, wvh, bv, vb);
    stats_kernel<<<dim3(16, BB), 256, 0, stream>>>(qhb, khb, smb, slb);
    attn_mfma_kernel<<<dim3(4, 32, BB), 256, 0, stream>>>(qhb, khb, vb, smb, slb, out);
}

// Round 6
// 280.451 us; speedup vs baseline: 8.7765x; 1.0737x over previous
//
#include <hip/hip_runtime.h>

// Problem constants
#define BB 16
#define CCH 512
#define CQD 32
#define HH 32
#define WW 32
#define NN 1024

typedef __attribute__((ext_vector_type(8))) _Float16 half8;
typedef __attribute__((ext_vector_type(4))) _Float16 half4;
typedef __attribute__((ext_vector_type(4))) float f32x4;

// ---------------------------------------------------------------------------
// prep_img: img[b][ci][h][w] fp32 -> imgh[b][h][w][ci] fp16 (ci contiguous)
// grid(32 h, 16 b), block 256
// ---------------------------------------------------------------------------
__global__ __launch_bounds__(256) void prep_img_kernel(
    const float* __restrict__ img, _Float16* __restrict__ imgh)
{
    const int h = blockIdx.x, b = blockIdx.y;
    __shared__ float X[64][33];
    const int t = threadIdx.x;
    for (int ci0 = 0; ci0 < CCH; ci0 += 64) {
        __syncthreads();
        #pragma unroll
        for (int i = 0; i < 8; ++i) {
            int ci = i * 8 + (t >> 5), w = t & 31;
            X[ci][w] = img[((size_t)(b * CCH + ci0 + ci) * HH + h) * WW + w];
        }
        __syncthreads();
        int w = t >> 3, g = t & 7;
        half8 o;
        #pragma unroll
        for (int u = 0; u < 8; ++u) o[u] = (_Float16)X[g * 8 + u][w];
        *(half8*)&imgh[(((size_t)b * HH + h) * WW + w) * CCH + ci0 + g * 8] = o;
    }
}

// ---------------------------------------------------------------------------
// prep_w: wv[co][ci][3][3] fp32 -> wvh[co][tap*512+ci] fp16. grid(512).
// ---------------------------------------------------------------------------
__global__ __launch_bounds__(256) void prep_w_kernel(
    const float* __restrict__ wv, _Float16* __restrict__ wvh)
{
    const int co = blockIdx.x;
    for (int idx = threadIdx.x; idx < 4608; idx += 256) {
        int tap = idx / 512, ci = idx - tap * 512;
        wvh[(size_t)co * 4608 + idx] = (_Float16)wv[(size_t)co * 4608 + ci * 9 + tap];
    }
}

// ---------------------------------------------------------------------------
// prep_wqk: wq,wk [32][512][3][3] -> wqkh[which*32+co][tap*512+ci]. grid(64).
// ---------------------------------------------------------------------------
__global__ __launch_bounds__(256) void prep_wqk_kernel(
    const float* __restrict__ wq, const float* __restrict__ wk,
    _Float16* __restrict__ wqkh)
{
    const int co = blockIdx.x;                 // 0..63
    const float* src = (co < 32) ? wq : wk;
    const int c = co & 31;
    for (int idx = threadIdx.x; idx < 4608; idx += 256) {
        int tap = idx / 512, ci = idx - tap * 512;
        wqkh[(size_t)co * 4608 + idx] = (_Float16)src[(size_t)c * 4608 + ci * 9 + tap];
    }
}

// ---------------------------------------------------------------------------
// conv_v_mfma: implicit-GEMM 3x3 conv via fp16 MFMA (unchanged from R5).
// ---------------------------------------------------------------------------
__global__ __launch_bounds__(256, 2) void conv_v_mfma_kernel(
    const _Float16* __restrict__ yh,    // [b][h][w][ci]
    const _Float16* __restrict__ wvh,   // [co][tap*512+ci]
    const float* __restrict__ bvb,
    _Float16* __restrict__ vout)        // fp16 [b][co][px]
{
    const int pt  = blockIdx.x;
    const int co0 = blockIdx.y * 64;
    const int b   = blockIdx.z;

    __shared__ _Float16 Wl[64 * 296];
    __shared__ _Float16 Yl[10 * 34 * 40];

    const int t    = threadIdx.x;
    const int lane = t & 63;
    const int wv4  = t >> 6;
    const int l15  = lane & 15;
    const int kg   = lane >> 4;

    f32x4 acc[4][4];
    #pragma unroll
    for (int m = 0; m < 4; ++m)
        #pragma unroll
        for (int n = 0; n < 4; ++n) {
            f32x4 z = {0.f, 0.f, 0.f, 0.f};
            acc[m][n] = z;
        }

    const int r0 = pt * 8;
    int bbase[4];
    #pragma unroll
    for (int n = 0; n < 4; ++n) {
        int pxl = wv4 * 64 + n * 16 + l15;
        int rl = pxl >> 5, cl = pxl & 31;
        bbase[n] = (rl * 34 + cl) * 40 + kg * 8;
    }
    int abase[4];
    #pragma unroll
    for (int m = 0; m < 4; ++m)
        abase[m] = (m * 16 + l15) * 296 + kg * 8;

    #pragma unroll 1
    for (int ci0 = 0; ci0 < CCH; ci0 += 32) {
        __syncthreads();
        #pragma unroll
        for (int i = 0; i < 9; ++i) {
            int idx = t + i * 256;
            int c = idx / 36, rem = idx - c * 36;
            int tap = rem >> 2, part = rem & 3;
            half8 v = *(const half8*)&wvh[(size_t)(co0 + c) * 4608 + tap * 512 + ci0 + part * 8];
            *(half8*)&Wl[c * 296 + tap * 32 + part * 8] = v;
        }
        for (int idx = t; idx < 1360; idx += 256) {
            int hw = idx >> 2, part = idx & 3;
            int r = hw / 34, c = hw - r * 34;
            int gh = r0 - 1 + r, gw = c - 1;
            half8 v;
            if (gh >= 0 && gh < HH && gw >= 0 && gw < WW) {
                v = *(const half8*)&yh[(((size_t)b * HH + gh) * WW + gw) * CCH + ci0 + part * 8];
            } else {
                #pragma unroll
                for (int u = 0; u < 8; ++u) v[u] = (_Float16)0.f;
            }
            *(half8*)&Yl[(r * 34 + c) * 40 + part * 8] = v;
        }
        __syncthreads();

        #pragma unroll
        for (int tap = 0; tap < 9; ++tap) {
            const int dh = tap / 3, dw = tap % 3;
            half8 a[4], bf[4];
            #pragma unroll
            for (int m = 0; m < 4; ++m)
                a[m] = *(const half8*)&Wl[abase[m] + tap * 32];
            #pragma unroll
            for (int n = 0; n < 4; ++n)
                bf[n] = *(const half8*)&Yl[bbase[n] + (dh * 34 + dw) * 40];
            #pragma unroll
            for (int m = 0; m < 4; ++m)
                #pragma unroll
                for (int n = 0; n < 4; ++n)
                    acc[m][n] = __builtin_amdgcn_mfma_f32_16x16x32_f16(a[m], bf[n], acc[m][n], 0, 0, 0);
        }
    }

    #pragma unroll
    for (int m = 0; m < 4; ++m) {
        #pragma unroll
        for (int reg = 0; reg < 4; ++reg) {
            int co = co0 + m * 16 + kg * 4 + reg;
            float bias = bvb[co];
            #pragma unroll
            for (int n = 0; n < 4; ++n) {
                int px = pt * 256 + wv4 * 64 + n * 16 + l15;
                vout[((size_t)b * CCH + co) * NN + px] = (_Float16)(acc[m][n][reg] + bias);
            }
        }
    }
}

// ---------------------------------------------------------------------------
// conv_qk_split: 32-co 3x3 conv via fp16 MFMA, SPLIT-K over ci (4 splits of
// 128 ci). Writes fp32 partials pbuf[ks][which][b][px][co].
// Block: 32 co x 128 px. grid(32 = 8pt*4ks, 2 which, 16 b), block 256.
// ---------------------------------------------------------------------------
__global__ __launch_bounds__(256, 4) void conv_qk_split_kernel(
    const _Float16* __restrict__ xh,    // [b][h][w][ci]
    const _Float16* __restrict__ yh,    // [b][h][w][ci]
    const _Float16* __restrict__ wqkh,  // [which*32+co][tap*512+ci]
    float* __restrict__ pbuf)           // [ks][which][b][px][co] fp32
{
    const int pt    = blockIdx.x >> 2;   // image rows pt*4 .. pt*4+3
    const int ks    = blockIdx.x & 3;    // ci split: ks*128 .. ks*128+127
    const int which = blockIdx.y;
    const int b     = blockIdx.z;
    const _Float16* in = which ? yh : xh;

    __shared__ _Float16 Wl[32 * 296];       // [co][9tap*32ci + 8pad]
    __shared__ _Float16 Xl[6 * 34 * 40];    // [row][col][32ci + 8pad]

    const int t    = threadIdx.x;
    const int lane = t & 63;
    const int w    = t >> 6;
    const int l15  = lane & 15;
    const int kg   = lane >> 4;

    f32x4 acc[2][2];
    #pragma unroll
    for (int m = 0; m < 2; ++m)
        #pragma unroll
        for (int n = 0; n < 2; ++n) {
            f32x4 z = {0.f, 0.f, 0.f, 0.f};
            acc[m][n] = z;
        }

    const int r0 = pt * 4;
    int bbase[2];
    #pragma unroll
    for (int n = 0; n < 2; ++n) {
        int pxl = w * 32 + n * 16 + l15;       // 0..127 local px
        int rl = pxl >> 5, cl = pxl & 31;
        bbase[n] = (rl * 34 + cl) * 40 + kg * 8;
    }
    int abase[2];
    #pragma unroll
    for (int m = 0; m < 2; ++m)
        abase[m] = (m * 16 + l15) * 296 + kg * 8;

    #pragma unroll 1
    for (int cc = 0; cc < 4; ++cc) {
        const int ci0 = ks * 128 + cc * 32;
        __syncthreads();
        // stage W: 32co x 9tap x 32ci = 1152 16B ops
        for (int idx = t; idx < 1152; idx += 256) {
            int c = idx / 36, rem = idx - c * 36;
            int tap = rem >> 2, part = rem & 3;
            half8 v = *(const half8*)&wqkh[(size_t)(which * 32 + c) * 4608 + tap * 512 + ci0 + part * 8];
            *(half8*)&Wl[c * 296 + tap * 32 + part * 8] = v;
        }
        // stage X: 6 rows x 34 cols x 32ci = 816 16B ops, zero halo
        for (int idx = t; idx < 816; idx += 256) {
            int hw = idx >> 2, part = idx & 3;
            int r = hw / 34, c = hw - r * 34;
            int gh = r0 - 1 + r, gw = c - 1;
            half8 v;
            if (gh >= 0 && gh < HH && gw >= 0 && gw < WW) {
                v = *(const half8*)&in[(((size_t)b * HH + gh) * WW + gw) * CCH + ci0 + part * 8];
            } else {
                #pragma unroll
                for (int u = 0; u < 8; ++u) v[u] = (_Float16)0.f;
            }
            *(half8*)&Xl[(r * 34 + c) * 40 + part * 8] = v;
        }
        __syncthreads();

        #pragma unroll
        for (int tap = 0; tap < 9; ++tap) {
            const int dh = tap / 3, dw = tap % 3;
            half8 a[2], bfr[2];
            #pragma unroll
            for (int m = 0; m < 2; ++m)
                a[m] = *(const half8*)&Wl[abase[m] + tap * 32];
            #pragma unroll
            for (int n = 0; n < 2; ++n)
                bfr[n] = *(const half8*)&Xl[bbase[n] + (dh * 34 + dw) * 40];
            #pragma unroll
            for (int m = 0; m < 2; ++m)
                #pragma unroll
                for (int n = 0; n < 2; ++n)
                    acc[m][n] = __builtin_amdgcn_mfma_f32_16x16x32_f16(a[m], bfr[n], acc[m][n], 0, 0, 0);
        }
    }

    // epilogue: partial fp32, D[row=co=m*16+kg*4..+3][col=px=n*16+l15]
    float* pb = &pbuf[(((size_t)(ks * 2 + which) * BB + b) * NN) * CQD];
    #pragma unroll
    for (int n = 0; n < 2; ++n) {
        int px = pt * 128 + w * 32 + n * 16 + l15;
        #pragma unroll
        for (int m = 0; m < 2; ++m) {
            float4 o = make_float4(acc[m][n][0], acc[m][n][1], acc[m][n][2], acc[m][n][3]);
            *(float4*)&pb[(size_t)px * CQD + m * 16 + kg * 4] = o;
        }
    }
}

// ---------------------------------------------------------------------------
// qk_reduce: sum 4 split-K partials + bias -> fp16 q/k [b][px][d].
// grid(1024), block 256. Each thread: one (which,b,px,co-quad).
// ---------------------------------------------------------------------------
__global__ __launch_bounds__(256) void qk_reduce_kernel(
    const float* __restrict__ pbuf,
    const float* __restrict__ bq, const float* __restrict__ bk,
    _Float16* __restrict__ qh, _Float16* __restrict__ kh)
{
    const int gid   = blockIdx.x * 256 + threadIdx.x;   // 0..262143
    const int cog   = gid & 7;
    const int px    = (gid >> 3) & 1023;
    const int b     = (gid >> 13) & 15;
    const int which = gid >> 17;

    const size_t base = (((size_t)which * BB + b) * NN + px) * CQD + cog * 4;
    const size_t kstep = (size_t)2 * BB * NN * CQD;
    float4 s = *(const float4*)&pbuf[base];
    #pragma unroll
    for (int ks = 1; ks < 4; ++ks) {
        float4 p = *(const float4*)&pbuf[base + ks * kstep];
        s.x += p.x; s.y += p.y; s.z += p.z; s.w += p.w;
    }
    const float* bias = which ? bk : bq;
    float4 bv = *(const float4*)&bias[cog * 4];
    half4 o;
    o[0] = (_Float16)(s.x + bv.x);
    o[1] = (_Float16)(s.y + bv.y);
    o[2] = (_Float16)(s.z + bv.z);
    o[3] = (_Float16)(s.w + bv.w);
    _Float16* out = which ? kh : qh;
    *(half4*)&out[((size_t)b * NN + px) * CQD + cog * 4] = o;
}

// ---------------------------------------------------------------------------
// stats: per (b,i) softmax row stats from fp16 q,k [b][n][d].
// grid(16 itiles, 16 b), block 256.
// ---------------------------------------------------------------------------
__global__ __launch_bounds__(256) void stats_kernel(
    const _Float16* __restrict__ qh, const _Float16* __restrict__ kh,
    float* __restrict__ sm, float* __restrict__ sl)
{
    const int i0 = blockIdx.x * 64;
    const int b  = blockIdx.y;

    __shared__ __align__(16) float qT[64][36];
    __shared__ __align__(16) float kT[128][36];
    __shared__ float redm[4][64];
    __shared__ float redl[4][64];

    const int t = threadIdx.x;
    {
        int ii = t >> 2, part = t & 3;
        half8 qv = *(const half8*)&qh[((size_t)b * NN + i0 + ii) * CQD + part * 8];
        #pragma unroll
        for (int u = 0; u < 8; ++u) qT[ii][part * 8 + u] = (float)qv[u];
    }
    __syncthreads();

    const int il = t & 63, js = t >> 6;
    float qr[32];
    #pragma unroll
    for (int v4 = 0; v4 < 8; ++v4) {
        float4 qv = *(const float4*)&qT[il][v4 * 4];
        qr[v4*4+0] = qv.x; qr[v4*4+1] = qv.y; qr[v4*4+2] = qv.z; qr[v4*4+3] = qv.w;
    }

    float m = -1e30f, l = 0.f;
    #pragma unroll 1
    for (int jc = 0; jc < 8; ++jc) {
        __syncthreads();
        #pragma unroll
        for (int r = 0; r < 2; ++r) {
            int idx = t + r * 256;
            int jj = idx >> 2, part = idx & 3;
            half8 kv = *(const half8*)&kh[((size_t)b * NN + jc * 128 + jj) * CQD + part * 8];
            #pragma unroll
            for (int u = 0; u < 8; ++u) kT[jj][part * 8 + u] = (float)kv[u];
        }
        __syncthreads();
        #pragma unroll 1
        for (int u = 0; u < 32; ++u) {
            int jj = js * 32 + u;
            float s = 0.f;
            #pragma unroll
            for (int v4 = 0; v4 < 8; ++v4) {
                float4 kv = *(const float4*)&kT[jj][v4 * 4];
                s += qr[v4*4+0]*kv.x + qr[v4*4+1]*kv.y + qr[v4*4+2]*kv.z + qr[v4*4+3]*kv.w;
            }
            if (s > m) { l = l * __expf(m - s) + 1.f; m = s; }
            else       { l += __expf(s - m); }
        }
    }
    redm[js][il] = m;
    redl[js][il] = l;
    __syncthreads();
    if (t < 64) {
        float M = redm[0][t];
        #pragma unroll
        for (int u = 1; u < 4; ++u) M = fmaxf(M, redm[u][t]);
        float L = 0.f;
        #pragma unroll
        for (int u = 0; u < 4; ++u) L += redl[u][t] * __expf(redm[u][t] - M);
        sm[(size_t)b * NN + i0 + t] = M;
        sl[(size_t)b * NN + i0 + t] = L;
    }
}

// ---------------------------------------------------------------------------
// attn_mfma: S = K.Q^T via MFMA (swapped), P = exp(S-m)/l packed fp16 to LDS,
// out = V.P via MFMA. Block: 128 c x 32 i, 4 waves (wave = 32c x 32i).
// grid(4 ctiles, 32 itiles, 16 b), block 256.
// ---------------------------------------------------------------------------
__global__ __launch_bounds__(256) void attn_mfma_kernel(
    const _Float16* __restrict__ qh,  // [b][i][d]
    const _Float16* __restrict__ kh,  // [b][j][d]
    const _Float16* __restrict__ v,   // [b][c][j]
    const float* __restrict__ sm, const float* __restrict__ sl,
    float* __restrict__ out)
{
    const int c0 = blockIdx.x * 128;
    const int i0 = blockIdx.y * 32;
    const int b  = blockIdx.z;

    __shared__ _Float16 Kl[64 * 40];    // [j][d+8pad]
    __shared__ _Float16 Vl[128 * 72];   // [c][j+8pad]
    __shared__ _Float16 Pl[32 * 72];    // [i][j+8pad]

    const int t    = threadIdx.x;
    const int lane = t & 63;
    const int w    = t >> 6;
    const int l15  = lane & 15;
    const int kg   = lane >> 4;

    half8 qb[2];
    float mr[2], rl[2];
    #pragma unroll
    for (int n = 0; n < 2; ++n) {
        int i = i0 + n * 16 + l15;
        qb[n] = *(const half8*)&qh[((size_t)b * NN + i) * CQD + kg * 8];
        mr[n] = sm[(size_t)b * NN + i];
        rl[n] = 1.f / sl[(size_t)b * NN + i];
    }

    f32x4 acc[2][2];
    #pragma unroll
    for (int m = 0; m < 2; ++m)
        #pragma unroll
        for (int n = 0; n < 2; ++n) {
            f32x4 z = {0.f, 0.f, 0.f, 0.f};
            acc[m][n] = z;
        }

    #pragma unroll 1
    for (int jt = 0; jt < 16; ++jt) {
        const int j0 = jt * 64;
        __syncthreads();
        {
            int j = t >> 2, part = t & 3;
            *(half8*)&Kl[j * 40 + part * 8] =
                *(const half8*)&kh[((size_t)b * NN + j0 + j) * CQD + part * 8];
        }
        #pragma unroll
        for (int r = 0; r < 4; ++r) {
            int idx = t + r * 256;
            int c = idx >> 3, jp = idx & 7;
            *(half8*)&Vl[c * 72 + jp * 8] =
                *(const half8*)&v[((size_t)b * CCH + c0 + c) * NN + j0 + jp * 8];
        }
        __syncthreads();

        // S phase (swapped): D[row=j=kg*4+reg][col=i=n*16+l15]
        {
            half8 ak = *(const half8*)&Kl[(w * 16 + l15) * 40 + kg * 8];
            #pragma unroll
            for (int n = 0; n < 2; ++n) {
                f32x4 s = {0.f, 0.f, 0.f, 0.f};
                s = __builtin_amdgcn_mfma_f32_16x16x32_f16(ak, qb[n], s, 0, 0, 0);
                half4 p4;
                #pragma unroll
                for (int reg = 0; reg < 4; ++reg)
                    p4[reg] = (_Float16)(__expf(s[reg] - mr[n]) * rl[n]);
                *(half4*)&Pl[(n * 16 + l15) * 72 + w * 16 + kg * 4] = p4;
            }
        }
        __syncthreads();

        // PV: out[c][i] += V[c][j] * P[j][i], K=64 (2 x K32)
        #pragma unroll
        for (int ks = 0; ks < 2; ++ks) {
            half8 pb[2], va[2];
            #pragma unroll
            for (int n = 0; n < 2; ++n)
                pb[n] = *(const half8*)&Pl[(n * 16 + l15) * 72 + ks * 32 + kg * 8];
            #pragma unroll
            for (int m = 0; m < 2; ++m)
                va[m] = *(const half8*)&Vl[(w * 32 + m * 16 + l15) * 72 + ks * 32 + kg * 8];
            #pragma unroll
            for (int m = 0; m < 2; ++m)
                #pragma unroll
                for (int n = 0; n < 2; ++n)
                    acc[m][n] = __builtin_amdgcn_mfma_f32_16x16x32_f16(va[m], pb[n], acc[m][n], 0, 0, 0);
        }
    }

    #pragma unroll
    for (int m = 0; m < 2; ++m)
        #pragma unroll
        for (int n = 0; n < 2; ++n)
            #pragma unroll
            for (int reg = 0; reg < 4; ++reg) {
                int c = c0 + w * 32 + m * 16 + kg * 4 + reg;
                out[((size_t)b * CCH + c) * NN + i0 + n * 16 + l15] = acc[m][n][reg];
            }
}

// ---------------------------------------------------------------------------
extern "C" void kernel_launch(void* const* d_in, const int* in_sizes, int n_in,
                              void* d_out, int out_size, void* d_ws, size_t ws_size,
                              hipStream_t stream) {
    const float* x  = (const float*)d_in[0];
    const float* y  = (const float*)d_in[1];
    const float* wq = (const float*)d_in[2];
    const float* bq = (const float*)d_in[3];
    const float* wk = (const float*)d_in[4];
    const float* bk = (const float*)d_in[5];
    const float* wv = (const float*)d_in[6];
    const float* bv = (const float*)d_in[7];
    float* out = (float*)d_out;

    // ws layout: qh(1M) kh(1M) sm/sl(128K) | v(16.8M) yh(16.8M) xh(16.8M)
    //            wvh(4.5M) wqkh(0.6M)
    // pbuf (split-K fp32 partials, 16.8M) ALIASES v: pbuf is consumed by
    // qk_reduce before conv_v_mfma writes v (same stream, serialized).
    _Float16* qhb = (_Float16*)d_ws;
    _Float16* khb = qhb + (size_t)BB * NN * CQD;
    float* smb = (float*)(khb + (size_t)BB * NN * CQD);
    float* slb = smb + (size_t)BB * NN;
    _Float16* vb   = (_Float16*)(slb + (size_t)BB * NN);
    _Float16* yhb  = vb + (size_t)BB * CCH * NN;
    _Float16* xhb  = yhb + (size_t)BB * NN * CCH;
    _Float16* wvh  = xhb + (size_t)BB * NN * CCH;
    _Float16* wqkh = wvh + (size_t)512 * 4608;
    float* pbuf = (float*)vb;

    prep_img_kernel<<<dim3(HH, BB), 256, 0, stream>>>(y, yhb);
    prep_img_kernel<<<dim3(HH, BB), 256, 0, stream>>>(x, xhb);
    prep_w_kernel<<<dim3(512), 256, 0, stream>>>(wv, wvh);
    prep_wqk_kernel<<<dim3(64), 256, 0, stream>>>(wq, wk, wqkh);
    conv_qk_split_kernel<<<dim3(32, 2, BB), 256, 0, stream>>>(xhb, yhb, wqkh, pbuf);
    qk_reduce_kernel<<<dim3(1024), 256, 0, stream>>>(pbuf, bq, bk, qhb, khb);
    conv_v_mfma_kernel<<<dim3(4, 8, BB), 256, 0, stream>>>(yhb, wvh, bv, vb);
    stats_kernel<<<dim3(16, BB), 256, 0, stream>>>(qhb, khb, smb, slb);
    attn_mfma_kernel<<<dim3(4, 32, BB), 256, 0, stream>>>(qhb, khb, vb, smb, slb, out);
}